// Round 4
// baseline (302.693 us; speedup 1.0000x reference)
//
#include <hip/hip_runtime.h>
#include <hip/hip_bf16.h>

typedef __hip_bfloat16 bf16;
typedef __attribute__((ext_vector_type(8))) short short8;
typedef __attribute__((ext_vector_type(4))) float f32x4;

static __device__ __forceinline__ float lrelu(float x){ return x > 0.f ? x : 0.2f * x; }

static __device__ __forceinline__ float ldf(const void* p, size_t i, int f32){
  return f32 ? ((const float*)p)[i] : __bfloat162float(((const bf16*)p)[i]);
}

static __device__ __forceinline__ float wsum(float v){
#pragma unroll
  for (int o = 32; o; o >>= 1) v += __shfl_xor(v, o, 64);
  return v;
}
static __device__ __forceinline__ float qsum(float v){
  v += __shfl_xor(v, 1); v += __shfl_xor(v, 2);
  v += __shfl_xor(v, 4); v += __shfl_xor(v, 8);
  return v;
}

static __device__ __forceinline__ unsigned short f2bf(float x){
  unsigned u = __float_as_uint(x);
  unsigned r = (u + 0x7fffu + ((u >> 16) & 1u)) >> 16;
  return (unsigned short)r;
}
static __device__ __forceinline__ float bfval(unsigned short h){
  return __uint_as_float(((unsigned)h) << 16);
}
static __device__ __forceinline__ unsigned packbf2(float a, float b){
  return ((unsigned)f2bf(b) << 16) | (unsigned)f2bf(a);
}
static __device__ __forceinline__ float unlo(unsigned v){ return __uint_as_float(v << 16); }
static __device__ __forceinline__ float unhi(unsigned v){ return __uint_as_float(v & 0xffff0000u); }

// ---------------- constants ----------------
#define CAP 10240          // binned slots per bucket (mean 8418, ~20 sigma)
#define EPB 16             // edges per thread in binscatter
#define CHUNK (256 * EPB)  // 4096 edges per block
#define PREPB 96           // prepw blocks in launch A
#define SORTCAP 9216       // LDS sort staging (8.7 sigma; global fallback beyond)

// ---------------- Launch A: prepw2 (blocks 0..95, self-detect) || binscatter ----------------
__global__ __launch_bounds__(256) void k_prep_scatter(
    const unsigned short* __restrict__ xprobe,
    const void* __restrict__ W1, const void* __restrict__ W2,
    int* __restrict__ flag,
    unsigned short* __restrict__ w1hi, unsigned short* __restrict__ w1lo,
    unsigned short* __restrict__ w2hi, unsigned short* __restrict__ w2lo,
    const int* __restrict__ ei, int* __restrict__ bucketCur,
    unsigned* __restrict__ binned, int E, int Etot){
  __shared__ int lcnt[256];
  __shared__ int lcur[256];
  int t = threadIdx.x;
  if (blockIdx.x < PREPB){
    // --- dtype probe: 512 halfwords of x. f32-as-bf16 trips ~123; true bf16 trips 0. ---
    if (t == 0) lcnt[0] = 0;
    __syncthreads();
    int bad = 0;
    for (int i = t; i < 512; i += 256){
      int e = (xprobe[i] >> 7) & 0xFF;
      if (e >= 133) bad++;
    }
    if (bad) atomicAdd(&lcnt[0], bad);
    __syncthreads();
    const int f = lcnt[0] > 8;
    if (blockIdx.x == 0 && t == 0) *flag = f;
    // --- prepw body ---
    int blk = blockIdx.x;
    const void* W; unsigned short *hi, *lo; int ncol, nct, tg;
    if (blk < 64){ W = W1; hi = w1hi; lo = w1lo; ncol = 128; nct = 8; tg = blk * 256 + t; }
    else         { W = W2; hi = w2hi; lo = w2lo; ncol = 64;  nct = 4; tg = (blk - 64) * 256 + t; }
    int j = tg & 7;
    int lane = (tg >> 3) & 63;
    int ct = (tg >> 9) % nct;
    int kc = tg / (512 * nct);
    int k = kc * 32 + ((lane >> 4) << 3) + j;
    int col = ct * 16 + (lane & 15);
    float w = ldf(W, (size_t)k * ncol + col, f);
    unsigned short h = f2bf(w);
    hi[tg] = h;
    lo[tg] = f2bf(w - bfval(h));
  } else {
    // --- binscatter body ---
    lcnt[t] = 0;
    __syncthreads();
    int base = (blockIdx.x - PREPB) * CHUNK;
    int vsrc[EPB], vdst[EPB];
#pragma unroll
    for (int k = 0; k < EPB; k++){
      int i = base + k * 256 + t;
      vdst[k] = -1;
      if (i < Etot){
        if (i < E){ vsrc[k] = ei[i]; vdst[k] = ei[E + i]; }
        else { vsrc[k] = i - E; vdst[k] = i - E; }
        atomicAdd(&lcnt[vdst[k] >> 8], 1);
      }
    }
    __syncthreads();
    lcur[t] = lcnt[t] ? atomicAdd(&bucketCur[t], lcnt[t]) : 0;
    __syncthreads();
#pragma unroll
    for (int k = 0; k < EPB; k++){
      if (vdst[k] >= 0){
        int b = vdst[k] >> 8;
        int p = atomicAdd(&lcur[b], 1);
        binned[(size_t)b * CAP + p] = (unsigned)vsrc[k] | ((unsigned)(vdst[k] & 255) << 24);
      }
    }
  }
}

// ---------------- Launch B: bucketsort (blocks 0..NBUCK-1) || gemm1m (MFMA bf16x3) ----------------
__global__ __launch_bounds__(256) void k_sort_gemm1(
    const int* __restrict__ bucketCur, const unsigned* __restrict__ binned,
    int* __restrict__ deg, int* __restrict__ offs, int* __restrict__ csr, int nbuck,
    const void* __restrict__ x,
    const unsigned short* __restrict__ whi, const unsigned short* __restrict__ wlo,
    const void* __restrict__ a_src1, const void* __restrict__ a_dst1,
    const int* __restrict__ flagp,
    unsigned* __restrict__ xh1p, float* __restrict__ ssrc1, float* __restrict__ sdst1, int n){
  __shared__ int smem[768 + SORTCAP];   // 39936 B: lcnt | lsc | lcur | lsrc
  int t = threadIdx.x;
  if ((int)blockIdx.x < nbuck){
    int* lcnt = smem;
    int* lsc  = smem + 256;
    int* lcur = smem + 512;
    int* lsrc = smem + 768;
    int b = blockIdx.x;
    int s0 = b * CAP;
    int cnt = bucketCur[b];
    int node0 = b << 8;
    lcnt[t] = 0;
    __syncthreads();
    for (int i = t; i < cnt; i += 256){
      unsigned v = binned[s0 + i];
      atomicAdd(&lcnt[v >> 24], 1);
    }
    __syncthreads();
    lsc[t] = lcnt[t];
    __syncthreads();
#pragma unroll
    for (int o = 1; o < 256; o <<= 1){
      int xv = (t >= o) ? lsc[t - o] : 0;
      __syncthreads();
      lsc[t] += xv;
      __syncthreads();
    }
    int excl = lsc[t] - lcnt[t];
    int node = node0 + t;
    if (node < n){ deg[node] = lcnt[t]; offs[node] = s0 + excl; }
    lcur[t] = excl;
    __syncthreads();
    if (cnt <= SORTCAP){
      for (int i = t; i < cnt; i += 256){
        unsigned v = binned[s0 + i];
        int p = atomicAdd(&lcur[v >> 24], 1);
        lsrc[p] = (int)(v & 0xFFFFFFu);
      }
      __syncthreads();
      for (int i = t; i < cnt; i += 256) csr[s0 + i] = lsrc[i];
    } else {
      for (int i = t; i < cnt; i += 256){
        unsigned v = binned[s0 + i];
        int p = atomicAdd(&lcur[v >> 24], 1);
        csr[s0 + p] = (int)(v & 0xFFFFFFu);
      }
    }
  } else {
    // --- gemm1m body ---
    const int f = *flagp;
    int lane = t & 63, w = t >> 6;
    int c16 = lane & 15, quad = lane >> 4;
    int nbw = (blockIdx.x - nbuck) * 64 + w * 16;
    int an = min(nbw + c16, n - 1);
    f32x4 acc[8];
#pragma unroll
    for (int ct = 0; ct < 8; ct++)
#pragma unroll
      for (int r = 0; r < 4; r++) acc[ct][r] = 0.f;

#pragma unroll
    for (int kc = 0; kc < 4; kc++){
      float av[8];
      short8 ahi, alo;
      if (f){
        const float* row = (const float*)x + (size_t)an * 128 + kc * 32 + quad * 8;
        float4 v0 = *(const float4*)row;
        float4 v1 = *(const float4*)(row + 4);
        av[0] = v0.x; av[1] = v0.y; av[2] = v0.z; av[3] = v0.w;
        av[4] = v1.x; av[5] = v1.y; av[6] = v1.z; av[7] = v1.w;
#pragma unroll
        for (int j = 0; j < 8; j++){
          unsigned short h = f2bf(av[j]);
          ahi[j] = (short)h;
          alo[j] = (short)f2bf(av[j] - bfval(h));
        }
      } else {
        const unsigned short* row = (const unsigned short*)x + (size_t)an * 128 + kc * 32 + quad * 8;
        uint4 v = *(const uint4*)row;
        ahi[0] = (short)(v.x & 0xffff); ahi[1] = (short)(v.x >> 16);
        ahi[2] = (short)(v.y & 0xffff); ahi[3] = (short)(v.y >> 16);
        ahi[4] = (short)(v.z & 0xffff); ahi[5] = (short)(v.z >> 16);
        ahi[6] = (short)(v.w & 0xffff); ahi[7] = (short)(v.w >> 16);
#pragma unroll
        for (int j = 0; j < 8; j++) alo[j] = 0;
      }
#pragma unroll
      for (int ct = 0; ct < 8; ct++){
        const short8 bhi = *(const short8*)(whi + (((size_t)(kc * 8 + ct) * 64 + lane) << 3));
        const short8 blo = *(const short8*)(wlo + (((size_t)(kc * 8 + ct) * 64 + lane) << 3));
        acc[ct] = __builtin_amdgcn_mfma_f32_16x16x32_bf16(ahi, blo, acc[ct], 0, 0, 0);
        acc[ct] = __builtin_amdgcn_mfma_f32_16x16x32_bf16(alo, bhi, acc[ct], 0, 0, 0);
        acc[ct] = __builtin_amdgcn_mfma_f32_16x16x32_bf16(ahi, bhi, acc[ct], 0, 0, 0);
      }
    }

    float as[8], ad[8];
#pragma unroll
    for (int ct = 0; ct < 8; ct++){
      as[ct] = ldf(a_src1, ct * 16 + c16, f);
      ad[ct] = ldf(a_dst1, ct * 16 + c16, f);
    }
    float vs0[4], vs1[4], vd0[4], vd1[4];
#pragma unroll
    for (int r = 0; r < 4; r++){
      float s0 = 0.f, s1 = 0.f, d0 = 0.f, d1 = 0.f;
#pragma unroll
      for (int ct = 0; ct < 4; ct++){
        s0 += acc[ct][r] * as[ct];         d0 += acc[ct][r] * ad[ct];
        s1 += acc[ct + 4][r] * as[ct + 4]; d1 += acc[ct + 4][r] * ad[ct + 4];
      }
      vs0[r] = qsum(s0); vs1[r] = qsum(s1);
      vd0[r] = qsum(d0); vd1[r] = qsum(d1);
    }
#pragma unroll
    for (int r = 0; r < 4; r++){
      int node = nbw + quad * 4 + r;
      if (node < n){
#pragma unroll
        for (int ct = 0; ct < 4; ct++)
          xh1p[(size_t)node * 64 + ct * 16 + c16] = packbf2(acc[ct][r], acc[ct + 4][r]);
      }
    }
    if (c16 == 0){
#pragma unroll
      for (int r = 0; r < 4; r++){
        int node = nbw + quad * 4 + r;
        if (node < n){
          ssrc1[node * 2]     = vs0[r];
          ssrc1[node * 2 + 1] = vs1[r];
          sdst1[node * 2]     = vd0[r];
          sdst1[node * 2 + 1] = vd1[r];
        }
      }
    }
  }
}

// ---------------- Layer-2 GEMM via MFMA: xh2 = h1(bf16) @ W2(hi+lo) + logits ----------------
__global__ __launch_bounds__(256) void k_gemm2m(
    const unsigned* __restrict__ h1p,
    const unsigned short* __restrict__ whi, const unsigned short* __restrict__ wlo,
    const void* __restrict__ a_src2, const void* __restrict__ a_dst2,
    const int* __restrict__ flagp,
    unsigned short* __restrict__ xh2b, float* __restrict__ ssrc2, float* __restrict__ sdst2, int n){
  const int f = *flagp;
  int t = threadIdx.x;
  int lane = t & 63, w = t >> 6;
  int c16 = lane & 15, quad = lane >> 4;
  int nbw = blockIdx.x * 64 + w * 16;
  int an = min(nbw + c16, n - 1);
  f32x4 acc[4];
#pragma unroll
  for (int ct = 0; ct < 4; ct++)
#pragma unroll
    for (int r = 0; r < 4; r++) acc[ct][r] = 0.f;

#pragma unroll
  for (int kc = 0; kc < 4; kc++){
    const uint4* hp = (const uint4*)h1p;
    uint4 v = hp[(size_t)an * 16 + kc * 4 + quad];
    short8 ahi;
    ahi[0] = (short)(v.x & 0xffff); ahi[1] = (short)(v.x >> 16);
    ahi[2] = (short)(v.y & 0xffff); ahi[3] = (short)(v.y >> 16);
    ahi[4] = (short)(v.z & 0xffff); ahi[5] = (short)(v.z >> 16);
    ahi[6] = (short)(v.w & 0xffff); ahi[7] = (short)(v.w >> 16);
#pragma unroll
    for (int ct = 0; ct < 4; ct++){
      const short8 bhi = *(const short8*)(whi + (((size_t)(kc * 4 + ct) * 64 + lane) << 3));
      const short8 blo = *(const short8*)(wlo + (((size_t)(kc * 4 + ct) * 64 + lane) << 3));
      acc[ct] = __builtin_amdgcn_mfma_f32_16x16x32_bf16(ahi, blo, acc[ct], 0, 0, 0);
      acc[ct] = __builtin_amdgcn_mfma_f32_16x16x32_bf16(ahi, bhi, acc[ct], 0, 0, 0);
    }
  }

  float as[4], ad[4];
#pragma unroll
  for (int ct = 0; ct < 4; ct++){
    as[ct] = ldf(a_src2, ct * 16 + c16, f);
    ad[ct] = ldf(a_dst2, ct * 16 + c16, f);
  }
  float vs[4], vd[4];
#pragma unroll
  for (int r = 0; r < 4; r++){
    float s = 0.f, d = 0.f;
#pragma unroll
    for (int ct = 0; ct < 4; ct++){
      s += acc[ct][r] * as[ct];
      d += acc[ct][r] * ad[ct];
    }
    vs[r] = qsum(s); vd[r] = qsum(d);
  }
#pragma unroll
  for (int r = 0; r < 4; r++){
    int node = nbw + quad * 4 + r;
    if (node < n){
#pragma unroll
      for (int ct = 0; ct < 4; ct++)
        xh2b[(size_t)node * 64 + ct * 16 + c16] = f2bf(acc[ct][r]);
    }
  }
  if (c16 == 0){
#pragma unroll
    for (int r = 0; r < 4; r++){
      int node = nbw + quad * 4 + r;
      if (node < n){ ssrc2[node] = vs[r]; sdst2[node] = vd[r]; }
    }
  }
}

// ---------------- Layer-1 aggregation v4: quarter-wave uint4 gathers + software pipeline ----------------
// Each 16-lane quarter reads one full 256B row (uint4/lane) -> 4 edges per load instr (was 2).
// Phases of 16 edges (4 loads); phase ph+1's loads issue BEFORE phase ph's FMAs so the compiler
// emits counted vmcnt instead of a full drain per phase. Edge weights re-read from LDS at
// consume time (not held across the wait) to keep VGPR <= 64; launch_bounds(256,8) pins 8 w/SIMD.
#define AG1_ISSUE(V0,V1,V2,V3,P) { \
  int b0_ = ((P) << 4) + qd; \
  V0 = *(const uint4*)(xb + ((__float_as_uint(stg[wv][b0_ +  0].x) << 8) + uoff)); \
  V1 = *(const uint4*)(xb + ((__float_as_uint(stg[wv][b0_ +  4].x) << 8) + uoff)); \
  V2 = *(const uint4*)(xb + ((__float_as_uint(stg[wv][b0_ +  8].x) << 8) + uoff)); \
  V3 = *(const uint4*)(xb + ((__float_as_uint(stg[wv][b0_ + 12].x) << 8) + uoff)); }
#define AG1_FMA1(V,SL) { \
  float4 w_ = stg[wv][SL]; float q0_ = w_.y, q1_ = w_.z; \
  a00 = fmaf(q0_, unlo(V.x), a00); a10 = fmaf(q1_, unhi(V.x), a10); \
  a01 = fmaf(q0_, unlo(V.y), a01); a11 = fmaf(q1_, unhi(V.y), a11); \
  a02 = fmaf(q0_, unlo(V.z), a02); a12 = fmaf(q1_, unhi(V.z), a12); \
  a03 = fmaf(q0_, unlo(V.w), a03); a13 = fmaf(q1_, unhi(V.w), a13); }
#define AG1_CONSUME(V0,V1,V2,V3,P) { \
  int c0_ = ((P) << 4) + qd; \
  AG1_FMA1(V0, c0_ + 0) AG1_FMA1(V1, c0_ + 4) AG1_FMA1(V2, c0_ + 8) AG1_FMA1(V3, c0_ + 12) }

__global__ __launch_bounds__(256, 8) void k_agg1(
    const int* __restrict__ offs, const int* __restrict__ deg, const int* __restrict__ csr,
    const float2* __restrict__ ssrc, const float2* __restrict__ sdst,
    const unsigned* __restrict__ xh1p, const void* __restrict__ b1,
    const int* __restrict__ flagp, unsigned* __restrict__ h1p, int n){
  __shared__ float4 stg[4][64];   // wave-private (s, p0, p1, -) per chunk edge
  int wv = threadIdx.x >> 6;
  int wid = (int)(((size_t)blockIdx.x * blockDim.x + threadIdx.x) >> 6);
  int lane = threadIdx.x & 63;
  if (wid >= n) return;
  int st = offs[wid], d = deg[wid];
  int u16 = lane & 15, qd = lane >> 4;
  float2 sd = sdst[wid];
  const char* __restrict__ xb = (const char*)xh1p;
  const unsigned uoff = (unsigned)u16 * 16u;   // uint4 per lane within the 256B row
  float Z0l = 0.f, Z1l = 0.f;
  float a00 = 0.f, a01 = 0.f, a02 = 0.f, a03 = 0.f;   // head0 ch 4*u16+j (this quarter's edges)
  float a10 = 0.f, a11 = 0.f, a12 = 0.f, a13 = 0.f;   // head1 ch 4*u16+j
  for (int base = 0; base < d; base += 64){
    int idx = base + lane;
    bool val = idx < d;
    int s = csr[st + (val ? idx : 0)];
    float2 sv = ssrc[s];
    float e0 = fminf(lrelu(sv.x + sd.x), 80.f);
    float e1 = fminf(lrelu(sv.y + sd.y), 80.f);
    float p0 = val ? __expf(e0) : 0.f;
    float p1 = val ? __expf(e1) : 0.f;
    Z0l += p0; Z1l += p1;
    float4 tv; tv.x = __uint_as_float((unsigned)s); tv.y = p0; tv.z = p1; tv.w = 0.f;
    stg[wv][lane] = tv;   // wave-private LDS, wave-synchronous: no barrier needed
    int cnt = min(64, d - base);
    int nph = (cnt + 15) >> 4;    // phases of 16 edges (4 uint4 loads each)
    uint4 vA0, vA1, vA2, vA3, vB0, vB1, vB2, vB3;
    AG1_ISSUE(vA0, vA1, vA2, vA3, 0)
    int ph = 0;
    for (; ph + 1 < nph; ph++){
      if (ph & 1){ AG1_ISSUE(vA0, vA1, vA2, vA3, ph + 1) AG1_CONSUME(vB0, vB1, vB2, vB3, ph) }
      else       { AG1_ISSUE(vB0, vB1, vB2, vB3, ph + 1) AG1_CONSUME(vA0, vA1, vA2, vA3, ph) }
    }
    if (ph & 1){ AG1_CONSUME(vB0, vB1, vB2, vB3, ph) }
    else       { AG1_CONSUME(vA0, vA1, vA2, vA3, ph) }
  }
  // reduce across the 4 quarters (lanes with same u16)
  a00 += __shfl_xor(a00, 16); a00 += __shfl_xor(a00, 32);
  a01 += __shfl_xor(a01, 16); a01 += __shfl_xor(a01, 32);
  a02 += __shfl_xor(a02, 16); a02 += __shfl_xor(a02, 32);
  a03 += __shfl_xor(a03, 16); a03 += __shfl_xor(a03, 32);
  a10 += __shfl_xor(a10, 16); a10 += __shfl_xor(a10, 32);
  a11 += __shfl_xor(a11, 16); a11 += __shfl_xor(a11, 32);
  a12 += __shfl_xor(a12, 16); a12 += __shfl_xor(a12, 32);
  a13 += __shfl_xor(a13, 16); a13 += __shfl_xor(a13, 32);
  float Z0 = wsum(Z0l), Z1 = wsum(Z1l);
  const int f = *flagp;
  if (qd < 2){
    // quarter 0 writes head0 (bytes 0..127), quarter 1 writes head1 (bytes 128..255)
    float Zh = qd ? Z1 : Z0;
    float inv = 1.f / (Zh + 1e-16f);
    float v0 = qd ? a10 : a00;
    float v1 = qd ? a11 : a01;
    float v2 = qd ? a12 : a02;
    float v3 = qd ? a13 : a03;
    int c0 = qd * 64 + 4 * u16;
    float h0 = fmaxf(v0 * inv + ldf(b1, c0 + 0, f), 0.f);
    float h1 = fmaxf(v1 * inv + ldf(b1, c0 + 1, f), 0.f);
    float h2 = fmaxf(v2 * inv + ldf(b1, c0 + 2, f), 0.f);
    float h3 = fmaxf(v3 * inv + ldf(b1, c0 + 3, f), 0.f);
    uint2 w; w.x = packbf2(h0, h1); w.y = packbf2(h2, h3);
    *(uint2*)((char*)h1p + (size_t)wid * 256 + (unsigned)(qd * 128 + u16 * 8)) = w;
  }
}

// ---------------- Layer-2 aggregation + fused heads v4: quarter-wave uint2 + pipeline ----------------
// Row = 128B: each 16-lane quarter reads one row (uint2/lane) -> 4 edges per load instr.
// Same phase/pipeline structure as k_agg1. Max staged slot = 63, so no zero pad needed.
#define AG2_ISSUE(V0,V1,V2,V3,P) { \
  int b0_ = ((P) << 4) + qd; \
  V0 = *(const uint2*)(xb + ((__float_as_uint(stg[wv][b0_ +  0].x) << 7) + uoff)); \
  V1 = *(const uint2*)(xb + ((__float_as_uint(stg[wv][b0_ +  4].x) << 7) + uoff)); \
  V2 = *(const uint2*)(xb + ((__float_as_uint(stg[wv][b0_ +  8].x) << 7) + uoff)); \
  V3 = *(const uint2*)(xb + ((__float_as_uint(stg[wv][b0_ + 12].x) << 7) + uoff)); }
#define AG2_FMA1(V,SL) { \
  float2 w_ = stg[wv][SL]; float q_ = w_.y; \
  c0a = fmaf(q_, unlo(V.x), c0a); c1a = fmaf(q_, unhi(V.x), c1a); \
  c2a = fmaf(q_, unlo(V.y), c2a); c3a = fmaf(q_, unhi(V.y), c3a); }
#define AG2_CONSUME(V0,V1,V2,V3,P) { \
  int c0_ = ((P) << 4) + qd; \
  AG2_FMA1(V0, c0_ + 0) AG2_FMA1(V1, c0_ + 4) AG2_FMA1(V2, c0_ + 8) AG2_FMA1(V3, c0_ + 12) }

__global__ __launch_bounds__(256, 8) void k_agg2(
    const int* __restrict__ offs, const int* __restrict__ deg, const int* __restrict__ csr,
    const float* __restrict__ ssrc, const float* __restrict__ sdstA,
    const unsigned short* __restrict__ xh2b, const void* __restrict__ bias2,
    const void* __restrict__ Wm, const void* __restrict__ bm,
    const void* __restrict__ Wlos, const void* __restrict__ bl,
    const int* __restrict__ flagp, void* __restrict__ out, int n){
  __shared__ float2 stg[4][64];   // wave-private (s, p) per chunk edge
  int wv = threadIdx.x >> 6;
  int wid = (int)(((size_t)blockIdx.x * blockDim.x + threadIdx.x) >> 6);
  int lane = threadIdx.x & 63;
  if (wid >= n) return;
  int st = offs[wid], d = deg[wid];
  int u16 = lane & 15, qd = lane >> 4;
  float sd = sdstA[wid];
  const char* __restrict__ xb = (const char*)xh2b;
  const unsigned uoff = (unsigned)u16 * 8u;   // uint2 per lane within the 128B row
  float Zl = 0.f;
  float c0a = 0.f, c1a = 0.f, c2a = 0.f, c3a = 0.f;   // ch 4*u16+j over this quarter's edges
  for (int base = 0; base < d; base += 64){
    int idx = base + lane;
    bool val = idx < d;
    int s = csr[st + (val ? idx : 0)];
    float e = fminf(lrelu(ssrc[s] + sd), 80.f);
    float pw = val ? __expf(e) : 0.f;
    Zl += pw;
    float2 tv; tv.x = __uint_as_float((unsigned)s); tv.y = pw;
    stg[wv][lane] = tv;
    int cnt = min(64, d - base);
    int nph = (cnt + 15) >> 4;
    uint2 vA0, vA1, vA2, vA3, vB0, vB1, vB2, vB3;
    AG2_ISSUE(vA0, vA1, vA2, vA3, 0)
    int ph = 0;
    for (; ph + 1 < nph; ph++){
      if (ph & 1){ AG2_ISSUE(vA0, vA1, vA2, vA3, ph + 1) AG2_CONSUME(vB0, vB1, vB2, vB3, ph) }
      else       { AG2_ISSUE(vB0, vB1, vB2, vB3, ph + 1) AG2_CONSUME(vA0, vA1, vA2, vA3, ph) }
    }
    if (ph & 1){ AG2_CONSUME(vB0, vB1, vB2, vB3, ph) }
    else       { AG2_CONSUME(vA0, vA1, vA2, vA3, ph) }
  }
  c0a += __shfl_xor(c0a, 16); c0a += __shfl_xor(c0a, 32);
  c1a += __shfl_xor(c1a, 16); c1a += __shfl_xor(c1a, 32);
  c2a += __shfl_xor(c2a, 16); c2a += __shfl_xor(c2a, 32);
  c3a += __shfl_xor(c3a, 16); c3a += __shfl_xor(c3a, 32);
  float Z = wsum(Zl);
  const int f = *flagp;
  float inv = 1.f / (Z + 1e-16f);
  int cch = 4 * u16;
  float h0 = fmaxf(c0a * inv + ldf(bias2, cch + 0, f), 0.f);
  float h1 = fmaxf(c1a * inv + ldf(bias2, cch + 1, f), 0.f);
  float h2 = fmaxf(c2a * inv + ldf(bias2, cch + 2, f), 0.f);
  float h3 = fmaxf(c3a * inv + ldf(bias2, cch + 3, f), 0.f);
  bool qz = (qd == 0);   // each channel counted exactly once across the wave
  float mo = wsum(qz ? h0 * ldf(Wm, cch, f) + h1 * ldf(Wm, cch + 1, f)
                     + h2 * ldf(Wm, cch + 2, f) + h3 * ldf(Wm, cch + 3, f) : 0.f);
  float l0 = wsum(qz ? h0 * ldf(Wlos, cch * 4 + 0, f) + h1 * ldf(Wlos, (cch + 1) * 4 + 0, f)
                     + h2 * ldf(Wlos, (cch + 2) * 4 + 0, f) + h3 * ldf(Wlos, (cch + 3) * 4 + 0, f) : 0.f);
  float l1 = wsum(qz ? h0 * ldf(Wlos, cch * 4 + 1, f) + h1 * ldf(Wlos, (cch + 1) * 4 + 1, f)
                     + h2 * ldf(Wlos, (cch + 2) * 4 + 1, f) + h3 * ldf(Wlos, (cch + 3) * 4 + 1, f) : 0.f);
  float l2 = wsum(qz ? h0 * ldf(Wlos, cch * 4 + 2, f) + h1 * ldf(Wlos, (cch + 1) * 4 + 2, f)
                     + h2 * ldf(Wlos, (cch + 2) * 4 + 2, f) + h3 * ldf(Wlos, (cch + 3) * 4 + 2, f) : 0.f);
  float l3 = wsum(qz ? h0 * ldf(Wlos, cch * 4 + 3, f) + h1 * ldf(Wlos, (cch + 1) * 4 + 3, f)
                     + h2 * ldf(Wlos, (cch + 2) * 4 + 3, f) + h3 * ldf(Wlos, (cch + 3) * 4 + 3, f) : 0.f);
  if (lane == 0){
    float vm = mo + ldf(bm, 0, f);
    float v0 = l0 + ldf(bl, 0, f);
    float v1 = l1 + ldf(bl, 1, f);
    float v2 = l2 + ldf(bl, 2, f);
    float v3 = l3 + ldf(bl, 3, f);
    if (f){
      float* o = (float*)out;
      o[wid] = vm;
      float4 lv = make_float4(v0, v1, v2, v3);
      *(float4*)&o[n + wid * 4] = lv;
    } else {
      bf16* o = (bf16*)out;
      o[wid] = __float2bfloat16(vm);
      o[n + wid * 4 + 0] = __float2bfloat16(v0); o[n + wid * 4 + 1] = __float2bfloat16(v1);
      o[n + wid * 4 + 2] = __float2bfloat16(v2); o[n + wid * 4 + 3] = __float2bfloat16(v3);
    }
  }
}

extern "C" void kernel_launch(void* const* d_in, const int* in_sizes, int n_in,
                              void* d_out, int out_size, void* d_ws, size_t ws_size,
                              hipStream_t stream){
  const void* x      = d_in[0];
  const int*  ei     = (const int*)d_in[1];
  const void* W1     = d_in[2];
  const void* a_src1 = d_in[3];
  const void* a_dst1 = d_in[4];
  const void* b1     = d_in[5];
  const void* W2     = d_in[6];
  const void* a_src2 = d_in[7];
  const void* a_dst2 = d_in[8];
  const void* bias2  = d_in[9];
  const void* Wm     = d_in[10];
  const void* bm     = d_in[11];
  const void* Wlos   = d_in[12];
  const void* bl     = d_in[13];

  const int N = in_sizes[0] / 128;
  const int E = in_sizes[1] / 2;
  const int Etot = E + N;
  const int NBUCK = (N + 255) >> 8;

  char* base = (char*)d_ws;
  size_t off = 0;
  auto alloc = [&](size_t bytes) -> void* {
    void* r = base + off;
    off += (bytes + 255) & ~(size_t)255;
    return r;
  };
  int*      flag  = (int*)alloc(256);
  unsigned* xh1p  = (unsigned*)alloc((size_t)N * 64 * 4);   // packed bf16x2 (both heads)
  unsigned* h1p   = (unsigned*)alloc((size_t)N * 64 * 4);   // h1 packed bf16 pairs
  float*    ssrc1 = (float*)alloc((size_t)N * 2 * 4);
  float*    sdst1 = (float*)alloc((size_t)N * 2 * 4);
  float*    ssrc2 = (float*)alloc((size_t)N * 4);
  float*    sdst2 = (float*)alloc((size_t)N * 4);
  int*      deg    = (int*)alloc((size_t)N * 4);
  int*      offsb  = (int*)alloc((size_t)N * 4);
  unsigned* binned = (unsigned*)alloc((size_t)NBUCK * CAP * 4);
  int*      csr    = (int*)alloc((size_t)NBUCK * CAP * 4);
  int*      bucketCur = (int*)alloc(1024);
  unsigned short* w1hi = (unsigned short*)alloc(16384 * 2);
  unsigned short* w1lo = (unsigned short*)alloc(16384 * 2);
  unsigned short* w2hi = (unsigned short*)alloc(8192 * 2);
  unsigned short* w2lo = (unsigned short*)alloc(8192 * 2);
  unsigned short* xh2b = (unsigned short*)xh1p;   // reuse after k_agg1

  const int nchunk = (Etot + CHUNK - 1) / CHUNK;
  const int ngemm1 = (N + 63) / 64;

  // zero bucket cursors (stream op, capture-safe)
  hipMemsetAsync(bucketCur, 0, (size_t)NBUCK * 4, stream);

  // Launch A: prepw2 (w/ inline dtype probe, flag publish) || binscatter
  k_prep_scatter<<<PREPB + nchunk, 256, 0, stream>>>(
      (const unsigned short*)x, W1, W2, flag, w1hi, w1lo, w2hi, w2lo,
      ei, bucketCur, binned, E, Etot);

  // Launch B: bucketsort || gemm1m
  k_sort_gemm1<<<NBUCK + ngemm1, 256, 0, stream>>>(
      bucketCur, binned, deg, offsb, csr, NBUCK,
      x, w1hi, w1lo, a_src1, a_dst1, flag, xh1p, ssrc1, sdst1, N);

  // Layer 1 aggregation (outputs packed bf16 h1)
  k_agg1<<<(N + 3) / 4, 256, 0, stream>>>(offsb, deg, csr, (const float2*)ssrc1, (const float2*)sdst1,
                                          xh1p, b1, flag, h1p, N);

  // Layer 2
  k_gemm2m<<<(N + 63) / 64, 256, 0, stream>>>(h1p, w2hi, w2lo, a_src2, a_dst2, flag, xh2b, ssrc2, sdst2, N);
  k_agg2<<<(N + 3) / 4, 256, 0, stream>>>(offsb, deg, csr, ssrc2, sdst2, xh2b, bias2,
                                          Wm, bm, Wlos, bl, flag, d_out, N);
}

// Round 5
// 278.993 us; speedup vs baseline: 1.0849x; 1.0849x over previous
//
#include <hip/hip_runtime.h>
#include <hip/hip_bf16.h>

typedef __hip_bfloat16 bf16;
typedef __attribute__((ext_vector_type(8))) short short8;
typedef __attribute__((ext_vector_type(4))) float f32x4;

static __device__ __forceinline__ float lrelu(float x){ return x > 0.f ? x : 0.2f * x; }

static __device__ __forceinline__ float ldf(const void* p, size_t i, int f32){
  return f32 ? ((const float*)p)[i] : __bfloat162float(((const bf16*)p)[i]);
}

static __device__ __forceinline__ float wsum(float v){
#pragma unroll
  for (int o = 32; o; o >>= 1) v += __shfl_xor(v, o, 64);
  return v;
}
static __device__ __forceinline__ float qsum(float v){
  v += __shfl_xor(v, 1); v += __shfl_xor(v, 2);
  v += __shfl_xor(v, 4); v += __shfl_xor(v, 8);
  return v;
}

static __device__ __forceinline__ unsigned short f2bf(float x){
  unsigned u = __float_as_uint(x);
  unsigned r = (u + 0x7fffu + ((u >> 16) & 1u)) >> 16;
  return (unsigned short)r;
}
static __device__ __forceinline__ float bfval(unsigned short h){
  return __uint_as_float(((unsigned)h) << 16);
}
static __device__ __forceinline__ unsigned packbf2(float a, float b){
  return ((unsigned)f2bf(b) << 16) | (unsigned)f2bf(a);
}
static __device__ __forceinline__ float unlo(unsigned v){ return __uint_as_float(v << 16); }
static __device__ __forceinline__ float unhi(unsigned v){ return __uint_as_float(v & 0xffff0000u); }

// ---------------- constants ----------------
#define CAP 10240          // binned slots per bucket (mean 8418, ~20 sigma)
#define EPB 16             // edges per thread in binscatter
#define CHUNK (256 * EPB)  // 4096 edges per block
#define PREPB 96           // prepw blocks in launch A
#define SORTCAP 9216       // LDS sort staging (8.7 sigma; global fallback beyond)

// ---------------- Launch A: prepw2 (blocks 0..95, self-detect) || binscatter ----------------
__global__ __launch_bounds__(256) void k_prep_scatter(
    const unsigned short* __restrict__ xprobe,
    const void* __restrict__ W1, const void* __restrict__ W2,
    int* __restrict__ flag,
    unsigned short* __restrict__ w1hi, unsigned short* __restrict__ w1lo,
    unsigned short* __restrict__ w2hi, unsigned short* __restrict__ w2lo,
    const int* __restrict__ ei, int* __restrict__ bucketCur,
    unsigned* __restrict__ binned, int E, int Etot){
  __shared__ int lcnt[256];
  __shared__ int lcur[256];
  int t = threadIdx.x;
  if (blockIdx.x < PREPB){
    // --- dtype probe: 512 halfwords of x. f32-as-bf16 trips ~123; true bf16 trips 0. ---
    if (t == 0) lcnt[0] = 0;
    __syncthreads();
    int bad = 0;
    for (int i = t; i < 512; i += 256){
      int e = (xprobe[i] >> 7) & 0xFF;
      if (e >= 133) bad++;
    }
    if (bad) atomicAdd(&lcnt[0], bad);
    __syncthreads();
    const int f = lcnt[0] > 8;
    if (blockIdx.x == 0 && t == 0) *flag = f;
    // --- prepw body ---
    int blk = blockIdx.x;
    const void* W; unsigned short *hi, *lo; int ncol, nct, tg;
    if (blk < 64){ W = W1; hi = w1hi; lo = w1lo; ncol = 128; nct = 8; tg = blk * 256 + t; }
    else         { W = W2; hi = w2hi; lo = w2lo; ncol = 64;  nct = 4; tg = (blk - 64) * 256 + t; }
    int j = tg & 7;
    int lane = (tg >> 3) & 63;
    int ct = (tg >> 9) % nct;
    int kc = tg / (512 * nct);
    int k = kc * 32 + ((lane >> 4) << 3) + j;
    int col = ct * 16 + (lane & 15);
    float w = ldf(W, (size_t)k * ncol + col, f);
    unsigned short h = f2bf(w);
    hi[tg] = h;
    lo[tg] = f2bf(w - bfval(h));
  } else {
    // --- binscatter body ---
    lcnt[t] = 0;
    __syncthreads();
    int base = (blockIdx.x - PREPB) * CHUNK;
    int vsrc[EPB], vdst[EPB];
#pragma unroll
    for (int k = 0; k < EPB; k++){
      int i = base + k * 256 + t;
      vdst[k] = -1;
      if (i < Etot){
        if (i < E){ vsrc[k] = ei[i]; vdst[k] = ei[E + i]; }
        else { vsrc[k] = i - E; vdst[k] = i - E; }
        atomicAdd(&lcnt[vdst[k] >> 8], 1);
      }
    }
    __syncthreads();
    lcur[t] = lcnt[t] ? atomicAdd(&bucketCur[t], lcnt[t]) : 0;
    __syncthreads();
#pragma unroll
    for (int k = 0; k < EPB; k++){
      if (vdst[k] >= 0){
        int b = vdst[k] >> 8;
        int p = atomicAdd(&lcur[b], 1);
        binned[(size_t)b * CAP + p] = (unsigned)vsrc[k] | ((unsigned)(vdst[k] & 255) << 24);
      }
    }
  }
}

// ---------------- Launch B: bucketsort (blocks 0..NBUCK-1) || gemm1m (MFMA bf16x3) ----------------
__global__ __launch_bounds__(256) void k_sort_gemm1(
    const int* __restrict__ bucketCur, const unsigned* __restrict__ binned,
    int* __restrict__ deg, int* __restrict__ offs, int* __restrict__ csr, int nbuck,
    const void* __restrict__ x,
    const unsigned short* __restrict__ whi, const unsigned short* __restrict__ wlo,
    const void* __restrict__ a_src1, const void* __restrict__ a_dst1,
    const int* __restrict__ flagp,
    unsigned* __restrict__ xh1p, float* __restrict__ ssrc1, float* __restrict__ sdst1, int n){
  __shared__ int smem[768 + SORTCAP];   // 39936 B: lcnt | lsc | lcur | lsrc
  int t = threadIdx.x;
  if ((int)blockIdx.x < nbuck){
    int* lcnt = smem;
    int* lsc  = smem + 256;
    int* lcur = smem + 512;
    int* lsrc = smem + 768;
    int b = blockIdx.x;
    int s0 = b * CAP;
    int cnt = bucketCur[b];
    int node0 = b << 8;
    lcnt[t] = 0;
    __syncthreads();
    for (int i = t; i < cnt; i += 256){
      unsigned v = binned[s0 + i];
      atomicAdd(&lcnt[v >> 24], 1);
    }
    __syncthreads();
    lsc[t] = lcnt[t];
    __syncthreads();
#pragma unroll
    for (int o = 1; o < 256; o <<= 1){
      int xv = (t >= o) ? lsc[t - o] : 0;
      __syncthreads();
      lsc[t] += xv;
      __syncthreads();
    }
    int excl = lsc[t] - lcnt[t];
    int node = node0 + t;
    if (node < n){ deg[node] = lcnt[t]; offs[node] = s0 + excl; }
    lcur[t] = excl;
    __syncthreads();
    if (cnt <= SORTCAP){
      for (int i = t; i < cnt; i += 256){
        unsigned v = binned[s0 + i];
        int p = atomicAdd(&lcur[v >> 24], 1);
        lsrc[p] = (int)(v & 0xFFFFFFu);
      }
      __syncthreads();
      for (int i = t; i < cnt; i += 256) csr[s0 + i] = lsrc[i];
    } else {
      for (int i = t; i < cnt; i += 256){
        unsigned v = binned[s0 + i];
        int p = atomicAdd(&lcur[v >> 24], 1);
        csr[s0 + p] = (int)(v & 0xFFFFFFu);
      }
    }
  } else {
    // --- gemm1m body ---
    const int f = *flagp;
    int lane = t & 63, w = t >> 6;
    int c16 = lane & 15, quad = lane >> 4;
    int nbw = (blockIdx.x - nbuck) * 64 + w * 16;
    int an = min(nbw + c16, n - 1);
    f32x4 acc[8];
#pragma unroll
    for (int ct = 0; ct < 8; ct++)
#pragma unroll
      for (int r = 0; r < 4; r++) acc[ct][r] = 0.f;

#pragma unroll
    for (int kc = 0; kc < 4; kc++){
      float av[8];
      short8 ahi, alo;
      if (f){
        const float* row = (const float*)x + (size_t)an * 128 + kc * 32 + quad * 8;
        float4 v0 = *(const float4*)row;
        float4 v1 = *(const float4*)(row + 4);
        av[0] = v0.x; av[1] = v0.y; av[2] = v0.z; av[3] = v0.w;
        av[4] = v1.x; av[5] = v1.y; av[6] = v1.z; av[7] = v1.w;
#pragma unroll
        for (int j = 0; j < 8; j++){
          unsigned short h = f2bf(av[j]);
          ahi[j] = (short)h;
          alo[j] = (short)f2bf(av[j] - bfval(h));
        }
      } else {
        const unsigned short* row = (const unsigned short*)x + (size_t)an * 128 + kc * 32 + quad * 8;
        uint4 v = *(const uint4*)row;
        ahi[0] = (short)(v.x & 0xffff); ahi[1] = (short)(v.x >> 16);
        ahi[2] = (short)(v.y & 0xffff); ahi[3] = (short)(v.y >> 16);
        ahi[4] = (short)(v.z & 0xffff); ahi[5] = (short)(v.z >> 16);
        ahi[6] = (short)(v.w & 0xffff); ahi[7] = (short)(v.w >> 16);
#pragma unroll
        for (int j = 0; j < 8; j++) alo[j] = 0;
      }
#pragma unroll
      for (int ct = 0; ct < 8; ct++){
        const short8 bhi = *(const short8*)(whi + (((size_t)(kc * 8 + ct) * 64 + lane) << 3));
        const short8 blo = *(const short8*)(wlo + (((size_t)(kc * 8 + ct) * 64 + lane) << 3));
        acc[ct] = __builtin_amdgcn_mfma_f32_16x16x32_bf16(ahi, blo, acc[ct], 0, 0, 0);
        acc[ct] = __builtin_amdgcn_mfma_f32_16x16x32_bf16(alo, bhi, acc[ct], 0, 0, 0);
        acc[ct] = __builtin_amdgcn_mfma_f32_16x16x32_bf16(ahi, bhi, acc[ct], 0, 0, 0);
      }
    }

    float as[8], ad[8];
#pragma unroll
    for (int ct = 0; ct < 8; ct++){
      as[ct] = ldf(a_src1, ct * 16 + c16, f);
      ad[ct] = ldf(a_dst1, ct * 16 + c16, f);
    }
    float vs0[4], vs1[4], vd0[4], vd1[4];
#pragma unroll
    for (int r = 0; r < 4; r++){
      float s0 = 0.f, s1 = 0.f, d0 = 0.f, d1 = 0.f;
#pragma unroll
      for (int ct = 0; ct < 4; ct++){
        s0 += acc[ct][r] * as[ct];         d0 += acc[ct][r] * ad[ct];
        s1 += acc[ct + 4][r] * as[ct + 4]; d1 += acc[ct + 4][r] * ad[ct + 4];
      }
      vs0[r] = qsum(s0); vs1[r] = qsum(s1);
      vd0[r] = qsum(d0); vd1[r] = qsum(d1);
    }
#pragma unroll
    for (int r = 0; r < 4; r++){
      int node = nbw + quad * 4 + r;
      if (node < n){
#pragma unroll
        for (int ct = 0; ct < 4; ct++)
          xh1p[(size_t)node * 64 + ct * 16 + c16] = packbf2(acc[ct][r], acc[ct + 4][r]);
      }
    }
    if (c16 == 0){
#pragma unroll
      for (int r = 0; r < 4; r++){
        int node = nbw + quad * 4 + r;
        if (node < n){
          ssrc1[node * 2]     = vs0[r];
          ssrc1[node * 2 + 1] = vs1[r];
          sdst1[node * 2]     = vd0[r];
          sdst1[node * 2 + 1] = vd1[r];
        }
      }
    }
  }
}

// ---------------- Layer-2 GEMM via MFMA: xh2 = h1(bf16) @ W2(hi+lo) + logits ----------------
__global__ __launch_bounds__(256) void k_gemm2m(
    const unsigned* __restrict__ h1p,
    const unsigned short* __restrict__ whi, const unsigned short* __restrict__ wlo,
    const void* __restrict__ a_src2, const void* __restrict__ a_dst2,
    const int* __restrict__ flagp,
    unsigned short* __restrict__ xh2b, float* __restrict__ ssrc2, float* __restrict__ sdst2, int n){
  const int f = *flagp;
  int t = threadIdx.x;
  int lane = t & 63, w = t >> 6;
  int c16 = lane & 15, quad = lane >> 4;
  int nbw = blockIdx.x * 64 + w * 16;
  int an = min(nbw + c16, n - 1);
  f32x4 acc[4];
#pragma unroll
  for (int ct = 0; ct < 4; ct++)
#pragma unroll
    for (int r = 0; r < 4; r++) acc[ct][r] = 0.f;

#pragma unroll
  for (int kc = 0; kc < 4; kc++){
    const uint4* hp = (const uint4*)h1p;
    uint4 v = hp[(size_t)an * 16 + kc * 4 + quad];
    short8 ahi;
    ahi[0] = (short)(v.x & 0xffff); ahi[1] = (short)(v.x >> 16);
    ahi[2] = (short)(v.y & 0xffff); ahi[3] = (short)(v.y >> 16);
    ahi[4] = (short)(v.z & 0xffff); ahi[5] = (short)(v.z >> 16);
    ahi[6] = (short)(v.w & 0xffff); ahi[7] = (short)(v.w >> 16);
#pragma unroll
    for (int ct = 0; ct < 4; ct++){
      const short8 bhi = *(const short8*)(whi + (((size_t)(kc * 4 + ct) * 64 + lane) << 3));
      const short8 blo = *(const short8*)(wlo + (((size_t)(kc * 4 + ct) * 64 + lane) << 3));
      acc[ct] = __builtin_amdgcn_mfma_f32_16x16x32_bf16(ahi, blo, acc[ct], 0, 0, 0);
      acc[ct] = __builtin_amdgcn_mfma_f32_16x16x32_bf16(ahi, bhi, acc[ct], 0, 0, 0);
    }
  }

  float as[4], ad[4];
#pragma unroll
  for (int ct = 0; ct < 4; ct++){
    as[ct] = ldf(a_src2, ct * 16 + c16, f);
    ad[ct] = ldf(a_dst2, ct * 16 + c16, f);
  }
  float vs[4], vd[4];
#pragma unroll
  for (int r = 0; r < 4; r++){
    float s = 0.f, d = 0.f;
#pragma unroll
    for (int ct = 0; ct < 4; ct++){
      s += acc[ct][r] * as[ct];
      d += acc[ct][r] * ad[ct];
    }
    vs[r] = qsum(s); vd[r] = qsum(d);
  }
#pragma unroll
  for (int r = 0; r < 4; r++){
    int node = nbw + quad * 4 + r;
    if (node < n){
#pragma unroll
      for (int ct = 0; ct < 4; ct++)
        xh2b[(size_t)node * 64 + ct * 16 + c16] = f2bf(acc[ct][r]);
    }
  }
  if (c16 == 0){
#pragma unroll
    for (int r = 0; r < 4; r++){
      int node = nbw + quad * 4 + r;
      if (node < n){ ssrc2[node] = vs[r]; sdst2[node] = vd[r]; }
    }
  }
}

// ---------------- Layer-1 aggregation v5: 2 nodes/wave, metadata-parallel + R2 gather loop ----------------
// Per-wave dependent chain was offs/deg(~900cy) -> csr(~900) -> ssrc(~300) -> gathers(~600):
// 2/3 metadata latency. v5 processes nodes A=2w, B=2w+1 per wave: both nodes' metadata, csr
// and ssrc loads issue in PARALLEL up front (one latency window), both chunk-0 edge sets are
// staged into separate LDS buffers, then A and B run the unchanged R2 half-wave gather loop.
// Register-light (~+8 VGPR vs R2's 36; NO explicit load pipeline -> no spill risk, cf. R4).
__global__ __launch_bounds__(256) void k_agg1(
    const int* __restrict__ offs, const int* __restrict__ deg, const int* __restrict__ csr,
    const float2* __restrict__ ssrc, const float2* __restrict__ sdst,
    const unsigned* __restrict__ xh1p, const void* __restrict__ b1,
    const int* __restrict__ flagp, unsigned* __restrict__ h1p, int n){
  __shared__ float4 stg[4][2][64];   // wave-private (s, p0, p1, -), one buffer per node
  int wv = threadIdx.x >> 6;
  int wave = (int)(((size_t)blockIdx.x * blockDim.x + threadIdx.x) >> 6);
  int lane = threadIdx.x & 63;
  int nA = wave * 2;
  if (nA >= n) return;
  int nB = nA + 1;
  bool hasB = nB < n;
  int nBc = hasB ? nB : nA;
  int half = lane >> 5, u = lane & 31;
  // --- metadata for both nodes (independent loads, one latency window) ---
  int stA = offs[nA], dA = deg[nA];
  int stB = offs[nBc];
  int dB = hasB ? deg[nBc] : 0;
  float2 sdA = sdst[nA];
  float2 sdB = sdst[nBc];
  const int f = *flagp;
  // --- chunk-0 csr for both (parallel) ---
  int sA = csr[stA + (lane < dA ? lane : 0)];
  int sB = csr[stB + (lane < dB ? lane : 0)];
  // --- ssrc gathers for both (parallel) ---
  float2 svA = ssrc[sA];
  float2 svB = ssrc[sB];
  // --- stage both chunk-0 buffers ---
  float ZA0 = 0.f, ZA1 = 0.f, ZB0 = 0.f, ZB1 = 0.f;
  {
    bool val = lane < dA;
    float p0 = val ? __expf(fminf(lrelu(svA.x + sdA.x), 80.f)) : 0.f;
    float p1 = val ? __expf(fminf(lrelu(svA.y + sdA.y), 80.f)) : 0.f;
    ZA0 = p0; ZA1 = p1;
    float4 tv; tv.x = __uint_as_float((unsigned)sA); tv.y = p0; tv.z = p1; tv.w = 0.f;
    stg[wv][0][lane] = tv;
  }
  {
    bool val = lane < dB;
    float p0 = val ? __expf(fminf(lrelu(svB.x + sdB.x), 80.f)) : 0.f;
    float p1 = val ? __expf(fminf(lrelu(svB.y + sdB.y), 80.f)) : 0.f;
    ZB0 = p0; ZB1 = p1;
    float4 tv; tv.x = __uint_as_float((unsigned)sB); tv.y = p0; tv.z = p1; tv.w = 0.f;
    stg[wv][1][lane] = tv;
  }
  const char* __restrict__ xb = (const char*)xh1p;
  const unsigned uoff = (unsigned)u * 8u;   // uint2 per lane within the 256B row
  float bx = ldf(b1, half * 64 + 2 * u, f);
  float by = ldf(b1, half * 64 + 2 * u + 1, f);
  // --- process A then B (R2 inner loop, unchanged semantics) ---
  for (int t = 0; t < 2; t++){
    if (t && !hasB) break;
    int node = nA + t;
    int st = t ? stB : stA;
    int d  = t ? dB  : dA;
    float2 sd = t ? sdB : sdA;
    float Z0l = t ? ZB0 : ZA0;
    float Z1l = t ? ZB1 : ZA1;
    float4* S = &stg[wv][t][0];
    float a0x = 0.f, a0y = 0.f, a1x = 0.f, a1y = 0.f;
    for (int base = 0; base < d; base += 64){
      if (base){   // chunks >0 are ~5-sigma rare (Poisson deg ~33); stage inline
        int idx = base + lane;
        bool val = idx < d;
        int s = csr[st + (val ? idx : 0)];
        float2 sv = ssrc[s];
        float p0 = val ? __expf(fminf(lrelu(sv.x + sd.x), 80.f)) : 0.f;
        float p1 = val ? __expf(fminf(lrelu(sv.y + sd.y), 80.f)) : 0.f;
        Z0l += p0; Z1l += p1;
        float4 tv; tv.x = __uint_as_float((unsigned)s); tv.y = p0; tv.z = p1; tv.w = 0.f;
        S[lane] = tv;
      }
      int cnt = min(64, d - base);
      int pairs = (cnt + 1) >> 1;
      for (int pj = 0; pj < pairs; pj += 8){
        unsigned offv[8]; float q0v[8], q1v[8]; uint2 vv[8];
#pragma unroll
        for (int k = 0; k < 8; k++){
          int jj = ((pj + k) << 1) + half;
          float4 v = S[jj];
          offv[k] = (__float_as_uint(v.x) << 8) + uoff;
          q0v[k] = v.y;
          q1v[k] = v.z;
        }
#pragma unroll
        for (int k = 0; k < 8; k++)
          vv[k] = *(const uint2*)(xb + offv[k]);
#pragma unroll
        for (int k = 0; k < 8; k++){
          a0x = fmaf(q0v[k], unlo(vv[k].x), a0x); a0y = fmaf(q0v[k], unlo(vv[k].y), a0y);
          a1x = fmaf(q1v[k], unhi(vv[k].x), a1x); a1y = fmaf(q1v[k], unhi(vv[k].y), a1y);
        }
      }
    }
    a0x += __shfl_xor(a0x, 32); a0y += __shfl_xor(a0y, 32);
    a1x += __shfl_xor(a1x, 32); a1y += __shfl_xor(a1y, 32);
    float Z0 = wsum(Z0l), Z1 = wsum(Z1l);
    float Zh = half ? Z1 : Z0;
    float ax = half ? a1x : a0x;
    float ay = half ? a1y : a0y;
    float inv = 1.f / (Zh + 1e-16f);
    float ox = fmaxf(ax * inv + bx, 0.f);
    float oy = fmaxf(ay * inv + by, 0.f);
    h1p[(size_t)node * 64 + half * 32 + u] = packbf2(ox, oy);
  }
}

// ---------------- Layer-2 aggregation + fused heads v5: 2 nodes/wave + R2 gather loop ----------------
// Same metadata-parallel structure as k_agg1 v5; inner loop is R2's 12-wide half-wave groups
// with the 96-slot zero pad (per node buffer).
__global__ __launch_bounds__(256) void k_agg2(
    const int* __restrict__ offs, const int* __restrict__ deg, const int* __restrict__ csr,
    const float* __restrict__ ssrc, const float* __restrict__ sdstA,
    const unsigned short* __restrict__ xh2b, const void* __restrict__ bias2,
    const void* __restrict__ Wm, const void* __restrict__ bm,
    const void* __restrict__ Wlos, const void* __restrict__ bl,
    const int* __restrict__ flagp, void* __restrict__ out, int n){
  __shared__ float2 stg[4][2][96];   // wave-private (s, p); [64..95] = zero pad
  int wv = threadIdx.x >> 6;
  int wave = (int)(((size_t)blockIdx.x * blockDim.x + threadIdx.x) >> 6);
  int lane = threadIdx.x & 63;
  int nA = wave * 2;
  if (nA >= n) return;
  int nB = nA + 1;
  bool hasB = nB < n;
  int nBc = hasB ? nB : nA;
  int half = lane >> 5, u = lane & 31;
  if (lane < 32){
    float2 z; z.x = __uint_as_float(0u); z.y = 0.f;
    stg[wv][0][64 + lane] = z;
    stg[wv][1][64 + lane] = z;
  }
  // --- metadata for both nodes (parallel) ---
  int stA = offs[nA], dA = deg[nA];
  int stB = offs[nBc];
  int dB = hasB ? deg[nBc] : 0;
  float sdA = sdstA[nA];
  float sdB = sdstA[nBc];
  const int f = *flagp;
  // --- chunk-0 csr + ssrc for both (parallel) ---
  int sA = csr[stA + (lane < dA ? lane : 0)];
  int sB = csr[stB + (lane < dB ? lane : 0)];
  float svA = ssrc[sA];
  float svB = ssrc[sB];
  float ZA = 0.f, ZB = 0.f;
  {
    bool val = lane < dA;
    float pw = val ? __expf(fminf(lrelu(svA + sdA), 80.f)) : 0.f;
    ZA = pw;
    float2 tv; tv.x = __uint_as_float((unsigned)sA); tv.y = pw;
    stg[wv][0][lane] = tv;
  }
  {
    bool val = lane < dB;
    float pw = val ? __expf(fminf(lrelu(svB + sdB), 80.f)) : 0.f;
    ZB = pw;
    float2 tv; tv.x = __uint_as_float((unsigned)sB); tv.y = pw;
    stg[wv][1][lane] = tv;
  }
  const char* __restrict__ xb = (const char*)xh2b;
  const unsigned uoff = (unsigned)u * 4u;   // packed bf16 pair per lane within the 128B row
  for (int t = 0; t < 2; t++){
    if (t && !hasB) break;
    int node = nA + t;
    int st = t ? stB : stA;
    int d  = t ? dB  : dA;
    float sd = t ? sdB : sdA;
    float Zl = t ? ZB : ZA;
    float2* S = &stg[wv][t][0];
    float ax = 0.f, ay = 0.f;
    for (int base = 0; base < d; base += 64){
      if (base){
        int idx = base + lane;
        bool val = idx < d;
        int s = csr[st + (val ? idx : 0)];
        float pw = val ? __expf(fminf(lrelu(ssrc[s] + sd), 80.f)) : 0.f;
        Zl += pw;
        float2 tv; tv.x = __uint_as_float((unsigned)s); tv.y = pw;
        S[lane] = tv;
      }
      int cnt = min(64, d - base);
      int pairs = (cnt + 1) >> 1;
      for (int pj = 0; pj < pairs; pj += 12){
        unsigned offv[12]; float qv[12]; unsigned vv[12];
#pragma unroll
        for (int k = 0; k < 12; k++){
          int jj = ((pj + k) << 1) + half;     // <= 85 < 96 (pad)
          float2 v = S[jj];
          offv[k] = (__float_as_uint(v.x) << 7) + uoff;
          qv[k] = v.y;
        }
#pragma unroll
        for (int k = 0; k < 12; k++)
          vv[k] = *(const unsigned*)(xb + offv[k]);
#pragma unroll
        for (int k = 0; k < 12; k++){
          ax = fmaf(qv[k], unlo(vv[k]), ax);
          ay = fmaf(qv[k], unhi(vv[k]), ay);
        }
      }
    }
    ax += __shfl_xor(ax, 32);
    ay += __shfl_xor(ay, 32);
    float Z = wsum(Zl);
    float inv = 1.f / (Z + 1e-16f);
    float hx = fmaxf(ax * inv + ldf(bias2, 2 * u, f), 0.f);
    float hy = fmaxf(ay * inv + ldf(bias2, 2 * u + 1, f), 0.f);
    bool lo32 = (half == 0);
    float mo = wsum(lo32 ? hx * ldf(Wm, 2 * u, f) + hy * ldf(Wm, 2 * u + 1, f) : 0.f);
    float l0 = wsum(lo32 ? hx * ldf(Wlos, (2 * u) * 4 + 0, f) + hy * ldf(Wlos, (2 * u + 1) * 4 + 0, f) : 0.f);
    float l1 = wsum(lo32 ? hx * ldf(Wlos, (2 * u) * 4 + 1, f) + hy * ldf(Wlos, (2 * u + 1) * 4 + 1, f) : 0.f);
    float l2 = wsum(lo32 ? hx * ldf(Wlos, (2 * u) * 4 + 2, f) + hy * ldf(Wlos, (2 * u + 1) * 4 + 2, f) : 0.f);
    float l3 = wsum(lo32 ? hx * ldf(Wlos, (2 * u) * 4 + 3, f) + hy * ldf(Wlos, (2 * u + 1) * 4 + 3, f) : 0.f);
    if (lane == 0){
      float vm = mo + ldf(bm, 0, f);
      float v0 = l0 + ldf(bl, 0, f);
      float v1 = l1 + ldf(bl, 1, f);
      float v2 = l2 + ldf(bl, 2, f);
      float v3 = l3 + ldf(bl, 3, f);
      if (f){
        float* o = (float*)out;
        o[node] = vm;
        float4 lv = make_float4(v0, v1, v2, v3);
        *(float4*)&o[n + node * 4] = lv;
      } else {
        bf16* o = (bf16*)out;
        o[node] = __float2bfloat16(vm);
        o[n + node * 4 + 0] = __float2bfloat16(v0); o[n + node * 4 + 1] = __float2bfloat16(v1);
        o[n + node * 4 + 2] = __float2bfloat16(v2); o[n + node * 4 + 3] = __float2bfloat16(v3);
      }
    }
  }
}

extern "C" void kernel_launch(void* const* d_in, const int* in_sizes, int n_in,
                              void* d_out, int out_size, void* d_ws, size_t ws_size,
                              hipStream_t stream){
  const void* x      = d_in[0];
  const int*  ei     = (const int*)d_in[1];
  const void* W1     = d_in[2];
  const void* a_src1 = d_in[3];
  const void* a_dst1 = d_in[4];
  const void* b1     = d_in[5];
  const void* W2     = d_in[6];
  const void* a_src2 = d_in[7];
  const void* a_dst2 = d_in[8];
  const void* bias2  = d_in[9];
  const void* Wm     = d_in[10];
  const void* bm     = d_in[11];
  const void* Wlos   = d_in[12];
  const void* bl     = d_in[13];

  const int N = in_sizes[0] / 128;
  const int E = in_sizes[1] / 2;
  const int Etot = E + N;
  const int NBUCK = (N + 255) >> 8;

  char* base = (char*)d_ws;
  size_t off = 0;
  auto alloc = [&](size_t bytes) -> void* {
    void* r = base + off;
    off += (bytes + 255) & ~(size_t)255;
    return r;
  };
  int*      flag  = (int*)alloc(256);
  unsigned* xh1p  = (unsigned*)alloc((size_t)N * 64 * 4);   // packed bf16x2 (both heads)
  unsigned* h1p   = (unsigned*)alloc((size_t)N * 64 * 4);   // h1 packed bf16 pairs
  float*    ssrc1 = (float*)alloc((size_t)N * 2 * 4);
  float*    sdst1 = (float*)alloc((size_t)N * 2 * 4);
  float*    ssrc2 = (float*)alloc((size_t)N * 4);
  float*    sdst2 = (float*)alloc((size_t)N * 4);
  int*      deg    = (int*)alloc((size_t)N * 4);
  int*      offsb  = (int*)alloc((size_t)N * 4);
  unsigned* binned = (unsigned*)alloc((size_t)NBUCK * CAP * 4);
  int*      csr    = (int*)alloc((size_t)NBUCK * CAP * 4);
  int*      bucketCur = (int*)alloc(1024);
  unsigned short* w1hi = (unsigned short*)alloc(16384 * 2);
  unsigned short* w1lo = (unsigned short*)alloc(16384 * 2);
  unsigned short* w2hi = (unsigned short*)alloc(8192 * 2);
  unsigned short* w2lo = (unsigned short*)alloc(8192 * 2);
  unsigned short* xh2b = (unsigned short*)xh1p;   // reuse after k_agg1

  const int nchunk = (Etot + CHUNK - 1) / CHUNK;
  const int ngemm1 = (N + 63) / 64;
  const int nwpair = (N + 1) / 2;              // 2 nodes per wave
  const int naggblk = (nwpair + 3) / 4;        // 4 waves per block

  // zero bucket cursors (stream op, capture-safe)
  hipMemsetAsync(bucketCur, 0, (size_t)NBUCK * 4, stream);

  // Launch A: prepw2 (w/ inline dtype probe, flag publish) || binscatter
  k_prep_scatter<<<PREPB + nchunk, 256, 0, stream>>>(
      (const unsigned short*)x, W1, W2, flag, w1hi, w1lo, w2hi, w2lo,
      ei, bucketCur, binned, E, Etot);

  // Launch B: bucketsort || gemm1m
  k_sort_gemm1<<<NBUCK + ngemm1, 256, 0, stream>>>(
      bucketCur, binned, deg, offsb, csr, NBUCK,
      x, w1hi, w1lo, a_src1, a_dst1, flag, xh1p, ssrc1, sdst1, N);

  // Layer 1 aggregation (outputs packed bf16 h1)
  k_agg1<<<naggblk, 256, 0, stream>>>(offsb, deg, csr, (const float2*)ssrc1, (const float2*)sdst1,
                                      xh1p, b1, flag, h1p, N);

  // Layer 2
  k_gemm2m<<<(N + 63) / 64, 256, 0, stream>>>(h1p, w2hi, w2lo, a_src2, a_dst2, flag, xh2b, ssrc2, sdst2, N);
  k_agg2<<<naggblk, 256, 0, stream>>>(offsb, deg, csr, ssrc2, sdst2, xh2b, bias2,
                                      Wm, bm, Wlos, bl, flag, d_out, N);
}

// Round 6
// 276.680 us; speedup vs baseline: 1.0940x; 1.0084x over previous
//
#include <hip/hip_runtime.h>
#include <hip/hip_bf16.h>

typedef __hip_bfloat16 bf16;
typedef __attribute__((ext_vector_type(8))) short short8;
typedef __attribute__((ext_vector_type(4))) float f32x4;

static __device__ __forceinline__ float lrelu(float x){ return x > 0.f ? x : 0.2f * x; }

static __device__ __forceinline__ float ldf(const void* p, size_t i, int f32){
  return f32 ? ((const float*)p)[i] : __bfloat162float(((const bf16*)p)[i]);
}

static __device__ __forceinline__ float wsum(float v){
#pragma unroll
  for (int o = 32; o; o >>= 1) v += __shfl_xor(v, o, 64);
  return v;
}
static __device__ __forceinline__ float qsum(float v){
  v += __shfl_xor(v, 1); v += __shfl_xor(v, 2);
  v += __shfl_xor(v, 4); v += __shfl_xor(v, 8);
  return v;
}

static __device__ __forceinline__ unsigned short f2bf(float x){
  unsigned u = __float_as_uint(x);
  unsigned r = (u + 0x7fffu + ((u >> 16) & 1u)) >> 16;
  return (unsigned short)r;
}
static __device__ __forceinline__ float bfval(unsigned short h){
  return __uint_as_float(((unsigned)h) << 16);
}
static __device__ __forceinline__ unsigned packbf2(float a, float b){
  return ((unsigned)f2bf(b) << 16) | (unsigned)f2bf(a);
}
static __device__ __forceinline__ float unlo(unsigned v){ return __uint_as_float(v << 16); }
static __device__ __forceinline__ float unhi(unsigned v){ return __uint_as_float(v & 0xffff0000u); }

// ---------------- constants ----------------
#define CAP 10240          // binned slots per bucket (mean 8418, ~20 sigma)
#define EPB 16             // edges per thread in binscatter
#define CHUNK (256 * EPB)  // 4096 edges per block
#define PREPB 96           // prepw blocks in launch A
#define SORTCAP 9216       // LDS sort staging (8.7 sigma; global fallback beyond)

// ---------------- Launch A: prepw2 (blocks 0..95, self-detect) || binscatter ----------------
__global__ __launch_bounds__(256) void k_prep_scatter(
    const unsigned short* __restrict__ xprobe,
    const void* __restrict__ W1, const void* __restrict__ W2,
    int* __restrict__ flag,
    unsigned short* __restrict__ w1hi, unsigned short* __restrict__ w1lo,
    unsigned short* __restrict__ w2hi, unsigned short* __restrict__ w2lo,
    const int* __restrict__ ei, int* __restrict__ bucketCur,
    unsigned* __restrict__ binned, int E, int Etot){
  __shared__ int lcnt[256];
  __shared__ int lcur[256];
  int t = threadIdx.x;
  if (blockIdx.x < PREPB){
    // --- dtype probe: 512 halfwords of x. f32-as-bf16 trips ~123; true bf16 trips 0. ---
    if (t == 0) lcnt[0] = 0;
    __syncthreads();
    int bad = 0;
    for (int i = t; i < 512; i += 256){
      int e = (xprobe[i] >> 7) & 0xFF;
      if (e >= 133) bad++;
    }
    if (bad) atomicAdd(&lcnt[0], bad);
    __syncthreads();
    const int f = lcnt[0] > 8;
    if (blockIdx.x == 0 && t == 0) *flag = f;
    // --- prepw body ---
    int blk = blockIdx.x;
    const void* W; unsigned short *hi, *lo; int ncol, nct, tg;
    if (blk < 64){ W = W1; hi = w1hi; lo = w1lo; ncol = 128; nct = 8; tg = blk * 256 + t; }
    else         { W = W2; hi = w2hi; lo = w2lo; ncol = 64;  nct = 4; tg = (blk - 64) * 256 + t; }
    int j = tg & 7;
    int lane = (tg >> 3) & 63;
    int ct = (tg >> 9) % nct;
    int kc = tg / (512 * nct);
    int k = kc * 32 + ((lane >> 4) << 3) + j;
    int col = ct * 16 + (lane & 15);
    float w = ldf(W, (size_t)k * ncol + col, f);
    unsigned short h = f2bf(w);
    hi[tg] = h;
    lo[tg] = f2bf(w - bfval(h));
  } else {
    // --- binscatter body ---
    lcnt[t] = 0;
    __syncthreads();
    int base = (blockIdx.x - PREPB) * CHUNK;
    int vsrc[EPB], vdst[EPB];
#pragma unroll
    for (int k = 0; k < EPB; k++){
      int i = base + k * 256 + t;
      vdst[k] = -1;
      if (i < Etot){
        if (i < E){ vsrc[k] = ei[i]; vdst[k] = ei[E + i]; }
        else { vsrc[k] = i - E; vdst[k] = i - E; }
        atomicAdd(&lcnt[vdst[k] >> 8], 1);
      }
    }
    __syncthreads();
    lcur[t] = lcnt[t] ? atomicAdd(&bucketCur[t], lcnt[t]) : 0;
    __syncthreads();
#pragma unroll
    for (int k = 0; k < EPB; k++){
      if (vdst[k] >= 0){
        int b = vdst[k] >> 8;
        int p = atomicAdd(&lcur[b], 1);
        binned[(size_t)b * CAP + p] = (unsigned)vsrc[k] | ((unsigned)(vdst[k] & 255) << 24);
      }
    }
  }
}

// ---------------- Launch B: bucketsort (blocks 0..NBUCK-1) || gemm1m (MFMA bf16x3) ----------------
__global__ __launch_bounds__(256) void k_sort_gemm1(
    const int* __restrict__ bucketCur, const unsigned* __restrict__ binned,
    int* __restrict__ deg, int* __restrict__ offs, int* __restrict__ csr, int nbuck,
    const void* __restrict__ x,
    const unsigned short* __restrict__ whi, const unsigned short* __restrict__ wlo,
    const void* __restrict__ a_src1, const void* __restrict__ a_dst1,
    const int* __restrict__ flagp,
    unsigned* __restrict__ xh1p, float* __restrict__ ssrc1, float* __restrict__ sdst1, int n){
  __shared__ int smem[768 + SORTCAP];   // 39936 B: lcnt | lsc | lcur | lsrc
  int t = threadIdx.x;
  if ((int)blockIdx.x < nbuck){
    int* lcnt = smem;
    int* lsc  = smem + 256;
    int* lcur = smem + 512;
    int* lsrc = smem + 768;
    int b = blockIdx.x;
    int s0 = b * CAP;
    int cnt = bucketCur[b];
    int node0 = b << 8;
    lcnt[t] = 0;
    __syncthreads();
    for (int i = t; i < cnt; i += 256){
      unsigned v = binned[s0 + i];
      atomicAdd(&lcnt[v >> 24], 1);
    }
    __syncthreads();
    lsc[t] = lcnt[t];
    __syncthreads();
#pragma unroll
    for (int o = 1; o < 256; o <<= 1){
      int xv = (t >= o) ? lsc[t - o] : 0;
      __syncthreads();
      lsc[t] += xv;
      __syncthreads();
    }
    int excl = lsc[t] - lcnt[t];
    int node = node0 + t;
    if (node < n){ deg[node] = lcnt[t]; offs[node] = s0 + excl; }
    lcur[t] = excl;
    __syncthreads();
    if (cnt <= SORTCAP){
      for (int i = t; i < cnt; i += 256){
        unsigned v = binned[s0 + i];
        int p = atomicAdd(&lcur[v >> 24], 1);
        lsrc[p] = (int)(v & 0xFFFFFFu);
      }
      __syncthreads();
      for (int i = t; i < cnt; i += 256) csr[s0 + i] = lsrc[i];
    } else {
      for (int i = t; i < cnt; i += 256){
        unsigned v = binned[s0 + i];
        int p = atomicAdd(&lcur[v >> 24], 1);
        csr[s0 + p] = (int)(v & 0xFFFFFFu);
      }
    }
  } else {
    // --- gemm1m body ---
    const int f = *flagp;
    int lane = t & 63, w = t >> 6;
    int c16 = lane & 15, quad = lane >> 4;
    int nbw = (blockIdx.x - nbuck) * 64 + w * 16;
    int an = min(nbw + c16, n - 1);
    f32x4 acc[8];
#pragma unroll
    for (int ct = 0; ct < 8; ct++)
#pragma unroll
      for (int r = 0; r < 4; r++) acc[ct][r] = 0.f;

#pragma unroll
    for (int kc = 0; kc < 4; kc++){
      float av[8];
      short8 ahi, alo;
      if (f){
        const float* row = (const float*)x + (size_t)an * 128 + kc * 32 + quad * 8;
        float4 v0 = *(const float4*)row;
        float4 v1 = *(const float4*)(row + 4);
        av[0] = v0.x; av[1] = v0.y; av[2] = v0.z; av[3] = v0.w;
        av[4] = v1.x; av[5] = v1.y; av[6] = v1.z; av[7] = v1.w;
#pragma unroll
        for (int j = 0; j < 8; j++){
          unsigned short h = f2bf(av[j]);
          ahi[j] = (short)h;
          alo[j] = (short)f2bf(av[j] - bfval(h));
        }
      } else {
        const unsigned short* row = (const unsigned short*)x + (size_t)an * 128 + kc * 32 + quad * 8;
        uint4 v = *(const uint4*)row;
        ahi[0] = (short)(v.x & 0xffff); ahi[1] = (short)(v.x >> 16);
        ahi[2] = (short)(v.y & 0xffff); ahi[3] = (short)(v.y >> 16);
        ahi[4] = (short)(v.z & 0xffff); ahi[5] = (short)(v.z >> 16);
        ahi[6] = (short)(v.w & 0xffff); ahi[7] = (short)(v.w >> 16);
#pragma unroll
        for (int j = 0; j < 8; j++) alo[j] = 0;
      }
#pragma unroll
      for (int ct = 0; ct < 8; ct++){
        const short8 bhi = *(const short8*)(whi + (((size_t)(kc * 8 + ct) * 64 + lane) << 3));
        const short8 blo = *(const short8*)(wlo + (((size_t)(kc * 8 + ct) * 64 + lane) << 3));
        acc[ct] = __builtin_amdgcn_mfma_f32_16x16x32_bf16(ahi, blo, acc[ct], 0, 0, 0);
        acc[ct] = __builtin_amdgcn_mfma_f32_16x16x32_bf16(alo, bhi, acc[ct], 0, 0, 0);
        acc[ct] = __builtin_amdgcn_mfma_f32_16x16x32_bf16(ahi, bhi, acc[ct], 0, 0, 0);
      }
    }

    float as[8], ad[8];
#pragma unroll
    for (int ct = 0; ct < 8; ct++){
      as[ct] = ldf(a_src1, ct * 16 + c16, f);
      ad[ct] = ldf(a_dst1, ct * 16 + c16, f);
    }
    float vs0[4], vs1[4], vd0[4], vd1[4];
#pragma unroll
    for (int r = 0; r < 4; r++){
      float s0 = 0.f, s1 = 0.f, d0 = 0.f, d1 = 0.f;
#pragma unroll
      for (int ct = 0; ct < 4; ct++){
        s0 += acc[ct][r] * as[ct];         d0 += acc[ct][r] * ad[ct];
        s1 += acc[ct + 4][r] * as[ct + 4]; d1 += acc[ct + 4][r] * ad[ct + 4];
      }
      vs0[r] = qsum(s0); vs1[r] = qsum(s1);
      vd0[r] = qsum(d0); vd1[r] = qsum(d1);
    }
#pragma unroll
    for (int r = 0; r < 4; r++){
      int node = nbw + quad * 4 + r;
      if (node < n){
#pragma unroll
        for (int ct = 0; ct < 4; ct++)
          xh1p[(size_t)node * 64 + ct * 16 + c16] = packbf2(acc[ct][r], acc[ct + 4][r]);
      }
    }
    if (c16 == 0){
#pragma unroll
      for (int r = 0; r < 4; r++){
        int node = nbw + quad * 4 + r;
        if (node < n){
          ssrc1[node * 2]     = vs0[r];
          ssrc1[node * 2 + 1] = vs1[r];
          sdst1[node * 2]     = vd0[r];
          sdst1[node * 2 + 1] = vd1[r];
        }
      }
    }
  }
}

// ---------------- Layer-2 GEMM via MFMA: xh2 = h1(bf16) @ W2(hi+lo) + logits ----------------
__global__ __launch_bounds__(256) void k_gemm2m(
    const unsigned* __restrict__ h1p,
    const unsigned short* __restrict__ whi, const unsigned short* __restrict__ wlo,
    const void* __restrict__ a_src2, const void* __restrict__ a_dst2,
    const int* __restrict__ flagp,
    unsigned short* __restrict__ xh2b, float* __restrict__ ssrc2, float* __restrict__ sdst2, int n){
  const int f = *flagp;
  int t = threadIdx.x;
  int lane = t & 63, w = t >> 6;
  int c16 = lane & 15, quad = lane >> 4;
  int nbw = blockIdx.x * 64 + w * 16;
  int an = min(nbw + c16, n - 1);
  f32x4 acc[4];
#pragma unroll
  for (int ct = 0; ct < 4; ct++)
#pragma unroll
    for (int r = 0; r < 4; r++) acc[ct][r] = 0.f;

#pragma unroll
  for (int kc = 0; kc < 4; kc++){
    const uint4* hp = (const uint4*)h1p;
    uint4 v = hp[(size_t)an * 16 + kc * 4 + quad];
    short8 ahi;
    ahi[0] = (short)(v.x & 0xffff); ahi[1] = (short)(v.x >> 16);
    ahi[2] = (short)(v.y & 0xffff); ahi[3] = (short)(v.y >> 16);
    ahi[4] = (short)(v.z & 0xffff); ahi[5] = (short)(v.z >> 16);
    ahi[6] = (short)(v.w & 0xffff); ahi[7] = (short)(v.w >> 16);
#pragma unroll
    for (int ct = 0; ct < 4; ct++){
      const short8 bhi = *(const short8*)(whi + (((size_t)(kc * 4 + ct) * 64 + lane) << 3));
      const short8 blo = *(const short8*)(wlo + (((size_t)(kc * 4 + ct) * 64 + lane) << 3));
      acc[ct] = __builtin_amdgcn_mfma_f32_16x16x32_bf16(ahi, blo, acc[ct], 0, 0, 0);
      acc[ct] = __builtin_amdgcn_mfma_f32_16x16x32_bf16(ahi, bhi, acc[ct], 0, 0, 0);
    }
  }

  float as[4], ad[4];
#pragma unroll
  for (int ct = 0; ct < 4; ct++){
    as[ct] = ldf(a_src2, ct * 16 + c16, f);
    ad[ct] = ldf(a_dst2, ct * 16 + c16, f);
  }
  float vs[4], vd[4];
#pragma unroll
  for (int r = 0; r < 4; r++){
    float s = 0.f, d = 0.f;
#pragma unroll
    for (int ct = 0; ct < 4; ct++){
      s += acc[ct][r] * as[ct];
      d += acc[ct][r] * ad[ct];
    }
    vs[r] = qsum(s); vd[r] = qsum(d);
  }
#pragma unroll
  for (int r = 0; r < 4; r++){
    int node = nbw + quad * 4 + r;
    if (node < n){
#pragma unroll
      for (int ct = 0; ct < 4; ct++)
        xh2b[(size_t)node * 64 + ct * 16 + c16] = f2bf(acc[ct][r]);
    }
  }
  if (c16 == 0){
#pragma unroll
    for (int r = 0; r < 4; r++){
      int node = nbw + quad * 4 + r;
      if (node < n){ ssrc2[node] = vs[r]; sdst2[node] = vd[r]; }
    }
  }
}

// ---------------- Layer-1 aggregation v6: R2 shell + double-buffered gather groups ----------------
// R2 structure (1 node/wave, half-wave pairs, groups of 8) but group g+1's 8 uint2 loads issue
// BEFORE group g's FMAs consume -> compiler emits counted s_waitcnt vmcnt(8), collapsing the
// 3 serial L3 windows per chunk to ~1. Buffers are NAMED uint2 (2x8x2=32 VGPR); edge weights
// re-read from LDS at consume so nothing else is live across the wait. Plain launch_bounds(256)
// (R4's (256,8) forced spills). Phantom pairs keep q=0 semantics (no tail body - R1 lesson).
#define AG1_LD(V,G) { \
  int b_ = ((G) << 4) + half; \
  V##0 = *(const uint2*)(xb + ((__float_as_uint(stg[wv][b_ +  0].x) << 8) + uoff)); \
  V##1 = *(const uint2*)(xb + ((__float_as_uint(stg[wv][b_ +  2].x) << 8) + uoff)); \
  V##2 = *(const uint2*)(xb + ((__float_as_uint(stg[wv][b_ +  4].x) << 8) + uoff)); \
  V##3 = *(const uint2*)(xb + ((__float_as_uint(stg[wv][b_ +  6].x) << 8) + uoff)); \
  V##4 = *(const uint2*)(xb + ((__float_as_uint(stg[wv][b_ +  8].x) << 8) + uoff)); \
  V##5 = *(const uint2*)(xb + ((__float_as_uint(stg[wv][b_ + 10].x) << 8) + uoff)); \
  V##6 = *(const uint2*)(xb + ((__float_as_uint(stg[wv][b_ + 12].x) << 8) + uoff)); \
  V##7 = *(const uint2*)(xb + ((__float_as_uint(stg[wv][b_ + 14].x) << 8) + uoff)); }
#define AG1_FM1(V,SL) { \
  float4 w_ = stg[wv][SL]; \
  a0x = fmaf(w_.y, unlo(V.x), a0x); a0y = fmaf(w_.y, unlo(V.y), a0y); \
  a1x = fmaf(w_.z, unhi(V.x), a1x); a1y = fmaf(w_.z, unhi(V.y), a1y); }
#define AG1_FM(V,G) { \
  int c_ = ((G) << 4) + half; \
  AG1_FM1(V##0, c_ +  0) AG1_FM1(V##1, c_ +  2) AG1_FM1(V##2, c_ +  4) AG1_FM1(V##3, c_ +  6) \
  AG1_FM1(V##4, c_ +  8) AG1_FM1(V##5, c_ + 10) AG1_FM1(V##6, c_ + 12) AG1_FM1(V##7, c_ + 14) }

__global__ __launch_bounds__(256) void k_agg1(
    const int* __restrict__ offs, const int* __restrict__ deg, const int* __restrict__ csr,
    const float2* __restrict__ ssrc, const float2* __restrict__ sdst,
    const unsigned* __restrict__ xh1p, const void* __restrict__ b1,
    const int* __restrict__ flagp, unsigned* __restrict__ h1p, int n){
  __shared__ float4 stg[4][64];   // wave-private (s, p0, p1, -) per chunk edge
  int wv = threadIdx.x >> 6;
  int wid = (int)(((size_t)blockIdx.x * blockDim.x + threadIdx.x) >> 6);
  int lane = threadIdx.x & 63;
  if (wid >= n) return;
  int st = offs[wid], d = deg[wid];
  int half = lane >> 5, u = lane & 31;
  float2 sd = sdst[wid];
  const char* __restrict__ xb = (const char*)xh1p;
  const unsigned uoff = (unsigned)u * 8u;   // uint2 per lane within the 256B row
  float Z0l = 0.f, Z1l = 0.f;
  float a0x = 0.f, a0y = 0.f, a1x = 0.f, a1y = 0.f;
  for (int base = 0; base < d; base += 64){
    int idx = base + lane;
    bool val = idx < d;
    int s = csr[st + (val ? idx : 0)];
    float2 sv = ssrc[s];
    float e0 = fminf(lrelu(sv.x + sd.x), 80.f);
    float e1 = fminf(lrelu(sv.y + sd.y), 80.f);
    float p0 = val ? __expf(e0) : 0.f;
    float p1 = val ? __expf(e1) : 0.f;
    Z0l += p0; Z1l += p1;
    float4 tv; tv.x = __uint_as_float((unsigned)s); tv.y = p0; tv.z = p1; tv.w = 0.f;
    stg[wv][lane] = tv;   // wave-private LDS, wave-synchronous: no barrier needed
    int cnt = min(64, d - base);
    int pairs = (cnt + 1) >> 1;
    int ngrp = (pairs + 7) >> 3;   // groups of 8 pairs; max slot (ngrp*16-2)+1 = 63
    uint2 vA0, vA1, vA2, vA3, vA4, vA5, vA6, vA7;
    uint2 vB0, vB1, vB2, vB3, vB4, vB5, vB6, vB7;
    AG1_LD(vA, 0)
    int g = 0;
    for (; g + 1 < ngrp; g++){
      if (g & 1){ AG1_LD(vA, g + 1) AG1_FM(vB, g) }
      else      { AG1_LD(vB, g + 1) AG1_FM(vA, g) }
    }
    if (g & 1){ AG1_FM(vB, g) }
    else      { AG1_FM(vA, g) }
  }
  a0x += __shfl_xor(a0x, 32); a0y += __shfl_xor(a0y, 32);
  a1x += __shfl_xor(a1x, 32); a1y += __shfl_xor(a1y, 32);
  float Z0 = wsum(Z0l), Z1 = wsum(Z1l);
  const int f = *flagp;
  float Zh = half ? Z1 : Z0;
  float ax = half ? a1x : a0x;
  float ay = half ? a1y : a0y;
  float inv = 1.f / (Zh + 1e-16f);
  float bx = ldf(b1, half * 64 + 2 * u, f);
  float by = ldf(b1, half * 64 + 2 * u + 1, f);
  float ox = fmaxf(ax * inv + bx, 0.f);
  float oy = fmaxf(ay * inv + by, 0.f);
  // packed bf16 pair store: pair index c = half*32+u <-> channels {2c, 2c+1}
  h1p[(size_t)wid * 64 + half * 32 + u] = packbf2(ox, oy);
}

// ---------------- Layer-2 aggregation + fused heads v6: R2 shell + double-buffered groups of 12 ----------------
// Same pipeline as k_agg1 v6; buffers are 12 named unsigned (2x12=24 VGPR). 96-slot zero pad
// retained (max slot = 2*24+22+1 = 71 < 96).
#define AG2_LD(V,G) { \
  int b_ = (G) * 24 + half; \
  V##0  = *(const unsigned*)(xb + ((__float_as_uint(stg[wv][b_ +  0].x) << 7) + uoff)); \
  V##1  = *(const unsigned*)(xb + ((__float_as_uint(stg[wv][b_ +  2].x) << 7) + uoff)); \
  V##2  = *(const unsigned*)(xb + ((__float_as_uint(stg[wv][b_ +  4].x) << 7) + uoff)); \
  V##3  = *(const unsigned*)(xb + ((__float_as_uint(stg[wv][b_ +  6].x) << 7) + uoff)); \
  V##4  = *(const unsigned*)(xb + ((__float_as_uint(stg[wv][b_ +  8].x) << 7) + uoff)); \
  V##5  = *(const unsigned*)(xb + ((__float_as_uint(stg[wv][b_ + 10].x) << 7) + uoff)); \
  V##6  = *(const unsigned*)(xb + ((__float_as_uint(stg[wv][b_ + 12].x) << 7) + uoff)); \
  V##7  = *(const unsigned*)(xb + ((__float_as_uint(stg[wv][b_ + 14].x) << 7) + uoff)); \
  V##8  = *(const unsigned*)(xb + ((__float_as_uint(stg[wv][b_ + 16].x) << 7) + uoff)); \
  V##9  = *(const unsigned*)(xb + ((__float_as_uint(stg[wv][b_ + 18].x) << 7) + uoff)); \
  V##10 = *(const unsigned*)(xb + ((__float_as_uint(stg[wv][b_ + 20].x) << 7) + uoff)); \
  V##11 = *(const unsigned*)(xb + ((__float_as_uint(stg[wv][b_ + 22].x) << 7) + uoff)); }
#define AG2_FM1(V,SL) { \
  float2 w_ = stg[wv][SL]; \
  ax = fmaf(w_.y, unlo(V), ax); ay = fmaf(w_.y, unhi(V), ay); }
#define AG2_FM(V,G) { \
  int c_ = (G) * 24 + half; \
  AG2_FM1(V##0,  c_ +  0) AG2_FM1(V##1,  c_ +  2) AG2_FM1(V##2,  c_ +  4) AG2_FM1(V##3,  c_ +  6) \
  AG2_FM1(V##4,  c_ +  8) AG2_FM1(V##5,  c_ + 10) AG2_FM1(V##6,  c_ + 12) AG2_FM1(V##7,  c_ + 14) \
  AG2_FM1(V##8,  c_ + 16) AG2_FM1(V##9,  c_ + 18) AG2_FM1(V##10, c_ + 20) AG2_FM1(V##11, c_ + 22) }

__global__ __launch_bounds__(256) void k_agg2(
    const int* __restrict__ offs, const int* __restrict__ deg, const int* __restrict__ csr,
    const float* __restrict__ ssrc, const float* __restrict__ sdstA,
    const unsigned short* __restrict__ xh2b, const void* __restrict__ bias2,
    const void* __restrict__ Wm, const void* __restrict__ bm,
    const void* __restrict__ Wlos, const void* __restrict__ bl,
    const int* __restrict__ flagp, void* __restrict__ out, int n){
  __shared__ float2 stg[4][96];   // wave-private (s, p); [64..95] = zero pad
  int wv = threadIdx.x >> 6;
  int wid = (int)(((size_t)blockIdx.x * blockDim.x + threadIdx.x) >> 6);
  int lane = threadIdx.x & 63;
  if (wid >= n) return;
  int st = offs[wid], d = deg[wid];
  int half = lane >> 5, u = lane & 31;
  if (lane < 32){ float2 z; z.x = __uint_as_float(0u); z.y = 0.f; stg[wv][64 + lane] = z; }
  float sd = sdstA[wid];
  const char* __restrict__ xb = (const char*)xh2b;
  const unsigned uoff = (unsigned)u * 4u;   // packed bf16 pair per lane within the 128B row
  float Zl = 0.f, ax = 0.f, ay = 0.f;
  for (int base = 0; base < d; base += 64){
    int idx = base + lane;
    bool val = idx < d;
    int s = csr[st + (val ? idx : 0)];
    float e = fminf(lrelu(ssrc[s] + sd), 80.f);
    float pw = val ? __expf(e) : 0.f;
    Zl += pw;
    float2 tv; tv.x = __uint_as_float((unsigned)s); tv.y = pw;
    stg[wv][lane] = tv;
    int cnt = min(64, d - base);
    int pairs = (cnt + 1) >> 1;
    int ngrp = (pairs + 11) / 12;
    unsigned vA0, vA1, vA2, vA3, vA4, vA5, vA6, vA7, vA8, vA9, vA10, vA11;
    unsigned vB0, vB1, vB2, vB3, vB4, vB5, vB6, vB7, vB8, vB9, vB10, vB11;
    AG2_LD(vA, 0)
    int g = 0;
    for (; g + 1 < ngrp; g++){
      if (g & 1){ AG2_LD(vA, g + 1) AG2_FM(vB, g) }
      else      { AG2_LD(vB, g + 1) AG2_FM(vA, g) }
    }
    if (g & 1){ AG2_FM(vB, g) }
    else      { AG2_FM(vA, g) }
  }
  ax += __shfl_xor(ax, 32);
  ay += __shfl_xor(ay, 32);
  float Z = wsum(Zl);
  const int f = *flagp;
  float inv = 1.f / (Z + 1e-16f);
  float hx = fmaxf(ax * inv + ldf(bias2, 2 * u, f), 0.f);
  float hy = fmaxf(ay * inv + ldf(bias2, 2 * u + 1, f), 0.f);
  bool lo32 = (half == 0);
  float mo = wsum(lo32 ? hx * ldf(Wm, 2 * u, f) + hy * ldf(Wm, 2 * u + 1, f) : 0.f);
  float l0 = wsum(lo32 ? hx * ldf(Wlos, (2 * u) * 4 + 0, f) + hy * ldf(Wlos, (2 * u + 1) * 4 + 0, f) : 0.f);
  float l1 = wsum(lo32 ? hx * ldf(Wlos, (2 * u) * 4 + 1, f) + hy * ldf(Wlos, (2 * u + 1) * 4 + 1, f) : 0.f);
  float l2 = wsum(lo32 ? hx * ldf(Wlos, (2 * u) * 4 + 2, f) + hy * ldf(Wlos, (2 * u + 1) * 4 + 2, f) : 0.f);
  float l3 = wsum(lo32 ? hx * ldf(Wlos, (2 * u) * 4 + 3, f) + hy * ldf(Wlos, (2 * u + 1) * 4 + 3, f) : 0.f);
  if (lane == 0){
    float vm = mo + ldf(bm, 0, f);
    float v0 = l0 + ldf(bl, 0, f);
    float v1 = l1 + ldf(bl, 1, f);
    float v2 = l2 + ldf(bl, 2, f);
    float v3 = l3 + ldf(bl, 3, f);
    if (f){
      float* o = (float*)out;
      o[wid] = vm;
      float4 lv = make_float4(v0, v1, v2, v3);
      *(float4*)&o[n + wid * 4] = lv;
    } else {
      bf16* o = (bf16*)out;
      o[wid] = __float2bfloat16(vm);
      o[n + wid * 4 + 0] = __float2bfloat16(v0); o[n + wid * 4 + 1] = __float2bfloat16(v1);
      o[n + wid * 4 + 2] = __float2bfloat16(v2); o[n + wid * 4 + 3] = __float2bfloat16(v3);
    }
  }
}

extern "C" void kernel_launch(void* const* d_in, const int* in_sizes, int n_in,
                              void* d_out, int out_size, void* d_ws, size_t ws_size,
                              hipStream_t stream){
  const void* x      = d_in[0];
  const int*  ei     = (const int*)d_in[1];
  const void* W1     = d_in[2];
  const void* a_src1 = d_in[3];
  const void* a_dst1 = d_in[4];
  const void* b1     = d_in[5];
  const void* W2     = d_in[6];
  const void* a_src2 = d_in[7];
  const void* a_dst2 = d_in[8];
  const void* bias2  = d_in[9];
  const void* Wm     = d_in[10];
  const void* bm     = d_in[11];
  const void* Wlos   = d_in[12];
  const void* bl     = d_in[13];

  const int N = in_sizes[0] / 128;
  const int E = in_sizes[1] / 2;
  const int Etot = E + N;
  const int NBUCK = (N + 255) >> 8;

  char* base = (char*)d_ws;
  size_t off = 0;
  auto alloc = [&](size_t bytes) -> void* {
    void* r = base + off;
    off += (bytes + 255) & ~(size_t)255;
    return r;
  };
  int*      flag  = (int*)alloc(256);
  unsigned* xh1p  = (unsigned*)alloc((size_t)N * 64 * 4);   // packed bf16x2 (both heads)
  unsigned* h1p   = (unsigned*)alloc((size_t)N * 64 * 4);   // h1 packed bf16 pairs
  float*    ssrc1 = (float*)alloc((size_t)N * 2 * 4);
  float*    sdst1 = (float*)alloc((size_t)N * 2 * 4);
  float*    ssrc2 = (float*)alloc((size_t)N * 4);
  float*    sdst2 = (float*)alloc((size_t)N * 4);
  int*      deg    = (int*)alloc((size_t)N * 4);
  int*      offsb  = (int*)alloc((size_t)N * 4);
  unsigned* binned = (unsigned*)alloc((size_t)NBUCK * CAP * 4);
  int*      csr    = (int*)alloc((size_t)NBUCK * CAP * 4);
  int*      bucketCur = (int*)alloc(1024);
  unsigned short* w1hi = (unsigned short*)alloc(16384 * 2);
  unsigned short* w1lo = (unsigned short*)alloc(16384 * 2);
  unsigned short* w2hi = (unsigned short*)alloc(8192 * 2);
  unsigned short* w2lo = (unsigned short*)alloc(8192 * 2);
  unsigned short* xh2b = (unsigned short*)xh1p;   // reuse after k_agg1

  const int nchunk = (Etot + CHUNK - 1) / CHUNK;
  const int ngemm1 = (N + 63) / 64;

  // zero bucket cursors (stream op, capture-safe)
  hipMemsetAsync(bucketCur, 0, (size_t)NBUCK * 4, stream);

  // Launch A: prepw2 (w/ inline dtype probe, flag publish) || binscatter
  k_prep_scatter<<<PREPB + nchunk, 256, 0, stream>>>(
      (const unsigned short*)x, W1, W2, flag, w1hi, w1lo, w2hi, w2lo,
      ei, bucketCur, binned, E, Etot);

  // Launch B: bucketsort || gemm1m
  k_sort_gemm1<<<NBUCK + ngemm1, 256, 0, stream>>>(
      bucketCur, binned, deg, offsb, csr, NBUCK,
      x, w1hi, w1lo, a_src1, a_dst1, flag, xh1p, ssrc1, sdst1, N);

  // Layer 1 aggregation (outputs packed bf16 h1)
  k_agg1<<<(N + 3) / 4, 256, 0, stream>>>(offsb, deg, csr, (const float2*)ssrc1, (const float2*)sdst1,
                                          xh1p, b1, flag, h1p, N);

  // Layer 2
  k_gemm2m<<<(N + 63) / 64, 256, 0, stream>>>(h1p, w2hi, w2lo, a_src2, a_dst2, flag, xh2b, ssrc2, sdst2, N);
  k_agg2<<<(N + 3) / 4, 256, 0, stream>>>(offsb, deg, csr, ssrc2, sdst2, xh2b, bias2,
                                          Wm, bm, Wlos, bl, flag, d_out, N);
}

// Round 7
// 258.662 us; speedup vs baseline: 1.1702x; 1.0697x over previous
//
#include <hip/hip_runtime.h>
#include <hip/hip_bf16.h>

typedef __hip_bfloat16 bf16;
typedef __attribute__((ext_vector_type(8))) short short8;
typedef __attribute__((ext_vector_type(4))) float f32x4;

static __device__ __forceinline__ float lrelu(float x){ return x > 0.f ? x : 0.2f * x; }

static __device__ __forceinline__ float ldf(const void* p, size_t i, int f32){
  return f32 ? ((const float*)p)[i] : __bfloat162float(((const bf16*)p)[i]);
}

static __device__ __forceinline__ float wsum(float v){
#pragma unroll
  for (int o = 32; o; o >>= 1) v += __shfl_xor(v, o, 64);
  return v;
}
static __device__ __forceinline__ float qsum(float v){
  v += __shfl_xor(v, 1); v += __shfl_xor(v, 2);
  v += __shfl_xor(v, 4); v += __shfl_xor(v, 8);
  return v;
}

static __device__ __forceinline__ unsigned short f2bf(float x){
  unsigned u = __float_as_uint(x);
  unsigned r = (u + 0x7fffu + ((u >> 16) & 1u)) >> 16;
  return (unsigned short)r;
}
static __device__ __forceinline__ float bfval(unsigned short h){
  return __uint_as_float(((unsigned)h) << 16);
}
static __device__ __forceinline__ unsigned packbf2(float a, float b){
  return ((unsigned)f2bf(b) << 16) | (unsigned)f2bf(a);
}
static __device__ __forceinline__ float unlo(unsigned v){ return __uint_as_float(v << 16); }
static __device__ __forceinline__ float unhi(unsigned v){ return __uint_as_float(v & 0xffff0000u); }

// ---------------- constants ----------------
#define CAP 10240          // binned slots per bucket (mean 8418, ~20 sigma)
#define EPB 16             // edges per thread in binscatter
#define CHUNK (256 * EPB)  // 4096 edges per block
#define PREPB 96           // prepw blocks in launch A
#define SORTCAP 9216       // LDS sort staging (8.7 sigma; global fallback beyond)

// ---------------- Launch A: prepw2 (blocks 0..95, self-detect) || binscatter ----------------
__global__ __launch_bounds__(256) void k_prep_scatter(
    const unsigned short* __restrict__ xprobe,
    const void* __restrict__ W1, const void* __restrict__ W2,
    int* __restrict__ flag,
    unsigned short* __restrict__ w1hi, unsigned short* __restrict__ w1lo,
    unsigned short* __restrict__ w2hi, unsigned short* __restrict__ w2lo,
    const int* __restrict__ ei, int* __restrict__ bucketCur,
    unsigned* __restrict__ binned, int E, int Etot){
  __shared__ int lcnt[256];
  __shared__ int lcur[256];
  int t = threadIdx.x;
  if (blockIdx.x < PREPB){
    // --- dtype probe: 512 halfwords of x. f32-as-bf16 trips ~123; true bf16 trips 0. ---
    if (t == 0) lcnt[0] = 0;
    __syncthreads();
    int bad = 0;
    for (int i = t; i < 512; i += 256){
      int e = (xprobe[i] >> 7) & 0xFF;
      if (e >= 133) bad++;
    }
    if (bad) atomicAdd(&lcnt[0], bad);
    __syncthreads();
    const int f = lcnt[0] > 8;
    if (blockIdx.x == 0 && t == 0) *flag = f;
    // --- prepw body ---
    int blk = blockIdx.x;
    const void* W; unsigned short *hi, *lo; int ncol, nct, tg;
    if (blk < 64){ W = W1; hi = w1hi; lo = w1lo; ncol = 128; nct = 8; tg = blk * 256 + t; }
    else         { W = W2; hi = w2hi; lo = w2lo; ncol = 64;  nct = 4; tg = (blk - 64) * 256 + t; }
    int j = tg & 7;
    int lane = (tg >> 3) & 63;
    int ct = (tg >> 9) % nct;
    int kc = tg / (512 * nct);
    int k = kc * 32 + ((lane >> 4) << 3) + j;
    int col = ct * 16 + (lane & 15);
    float w = ldf(W, (size_t)k * ncol + col, f);
    unsigned short h = f2bf(w);
    hi[tg] = h;
    lo[tg] = f2bf(w - bfval(h));
  } else {
    // --- binscatter body ---
    lcnt[t] = 0;
    __syncthreads();
    int base = (blockIdx.x - PREPB) * CHUNK;
    int vsrc[EPB], vdst[EPB];
#pragma unroll
    for (int k = 0; k < EPB; k++){
      int i = base + k * 256 + t;
      vdst[k] = -1;
      if (i < Etot){
        if (i < E){ vsrc[k] = ei[i]; vdst[k] = ei[E + i]; }
        else { vsrc[k] = i - E; vdst[k] = i - E; }
        atomicAdd(&lcnt[vdst[k] >> 8], 1);
      }
    }
    __syncthreads();
    lcur[t] = lcnt[t] ? atomicAdd(&bucketCur[t], lcnt[t]) : 0;
    __syncthreads();
#pragma unroll
    for (int k = 0; k < EPB; k++){
      if (vdst[k] >= 0){
        int b = vdst[k] >> 8;
        int p = atomicAdd(&lcur[b], 1);
        binned[(size_t)b * CAP + p] = (unsigned)vsrc[k] | ((unsigned)(vdst[k] & 255) << 24);
      }
    }
  }
}

// ---------------- Launch B: bucketsort (blocks 0..NBUCK-1) || gemm1m (MFMA bf16x3) ----------------
__global__ __launch_bounds__(256) void k_sort_gemm1(
    const int* __restrict__ bucketCur, const unsigned* __restrict__ binned,
    int* __restrict__ deg, int* __restrict__ offs, int* __restrict__ csr, int nbuck,
    const void* __restrict__ x,
    const unsigned short* __restrict__ whi, const unsigned short* __restrict__ wlo,
    const void* __restrict__ a_src1, const void* __restrict__ a_dst1,
    const int* __restrict__ flagp,
    unsigned* __restrict__ xh1p, float* __restrict__ ssrc1, float* __restrict__ sdst1, int n){
  __shared__ int smem[768 + SORTCAP];   // 39936 B: lcnt | lsc | lcur | lsrc
  int t = threadIdx.x;
  if ((int)blockIdx.x < nbuck){
    int* lcnt = smem;
    int* lsc  = smem + 256;
    int* lcur = smem + 512;
    int* lsrc = smem + 768;
    int b = blockIdx.x;
    int s0 = b * CAP;
    int cnt = bucketCur[b];
    int node0 = b << 8;
    lcnt[t] = 0;
    __syncthreads();
    for (int i = t; i < cnt; i += 256){
      unsigned v = binned[s0 + i];
      atomicAdd(&lcnt[v >> 24], 1);
    }
    __syncthreads();
    lsc[t] = lcnt[t];
    __syncthreads();
#pragma unroll
    for (int o = 1; o < 256; o <<= 1){
      int xv = (t >= o) ? lsc[t - o] : 0;
      __syncthreads();
      lsc[t] += xv;
      __syncthreads();
    }
    int excl = lsc[t] - lcnt[t];
    int node = node0 + t;
    if (node < n){ deg[node] = lcnt[t]; offs[node] = s0 + excl; }
    lcur[t] = excl;
    __syncthreads();
    if (cnt <= SORTCAP){
      for (int i = t; i < cnt; i += 256){
        unsigned v = binned[s0 + i];
        int p = atomicAdd(&lcur[v >> 24], 1);
        lsrc[p] = (int)(v & 0xFFFFFFu);
      }
      __syncthreads();
      for (int i = t; i < cnt; i += 256) csr[s0 + i] = lsrc[i];
    } else {
      for (int i = t; i < cnt; i += 256){
        unsigned v = binned[s0 + i];
        int p = atomicAdd(&lcur[v >> 24], 1);
        csr[s0 + p] = (int)(v & 0xFFFFFFu);
      }
    }
  } else {
    // --- gemm1m body ---
    const int f = *flagp;
    int lane = t & 63, w = t >> 6;
    int c16 = lane & 15, quad = lane >> 4;
    int nbw = (blockIdx.x - nbuck) * 64 + w * 16;
    int an = min(nbw + c16, n - 1);
    f32x4 acc[8];
#pragma unroll
    for (int ct = 0; ct < 8; ct++)
#pragma unroll
      for (int r = 0; r < 4; r++) acc[ct][r] = 0.f;

#pragma unroll
    for (int kc = 0; kc < 4; kc++){
      float av[8];
      short8 ahi, alo;
      if (f){
        const float* row = (const float*)x + (size_t)an * 128 + kc * 32 + quad * 8;
        float4 v0 = *(const float4*)row;
        float4 v1 = *(const float4*)(row + 4);
        av[0] = v0.x; av[1] = v0.y; av[2] = v0.z; av[3] = v0.w;
        av[4] = v1.x; av[5] = v1.y; av[6] = v1.z; av[7] = v1.w;
#pragma unroll
        for (int j = 0; j < 8; j++){
          unsigned short h = f2bf(av[j]);
          ahi[j] = (short)h;
          alo[j] = (short)f2bf(av[j] - bfval(h));
        }
      } else {
        const unsigned short* row = (const unsigned short*)x + (size_t)an * 128 + kc * 32 + quad * 8;
        uint4 v = *(const uint4*)row;
        ahi[0] = (short)(v.x & 0xffff); ahi[1] = (short)(v.x >> 16);
        ahi[2] = (short)(v.y & 0xffff); ahi[3] = (short)(v.y >> 16);
        ahi[4] = (short)(v.z & 0xffff); ahi[5] = (short)(v.z >> 16);
        ahi[6] = (short)(v.w & 0xffff); ahi[7] = (short)(v.w >> 16);
#pragma unroll
        for (int j = 0; j < 8; j++) alo[j] = 0;
      }
#pragma unroll
      for (int ct = 0; ct < 8; ct++){
        const short8 bhi = *(const short8*)(whi + (((size_t)(kc * 8 + ct) * 64 + lane) << 3));
        const short8 blo = *(const short8*)(wlo + (((size_t)(kc * 8 + ct) * 64 + lane) << 3));
        acc[ct] = __builtin_amdgcn_mfma_f32_16x16x32_bf16(ahi, blo, acc[ct], 0, 0, 0);
        acc[ct] = __builtin_amdgcn_mfma_f32_16x16x32_bf16(alo, bhi, acc[ct], 0, 0, 0);
        acc[ct] = __builtin_amdgcn_mfma_f32_16x16x32_bf16(ahi, bhi, acc[ct], 0, 0, 0);
      }
    }

    float as[8], ad[8];
#pragma unroll
    for (int ct = 0; ct < 8; ct++){
      as[ct] = ldf(a_src1, ct * 16 + c16, f);
      ad[ct] = ldf(a_dst1, ct * 16 + c16, f);
    }
    float vs0[4], vs1[4], vd0[4], vd1[4];
#pragma unroll
    for (int r = 0; r < 4; r++){
      float s0 = 0.f, s1 = 0.f, d0 = 0.f, d1 = 0.f;
#pragma unroll
      for (int ct = 0; ct < 4; ct++){
        s0 += acc[ct][r] * as[ct];         d0 += acc[ct][r] * ad[ct];
        s1 += acc[ct + 4][r] * as[ct + 4]; d1 += acc[ct + 4][r] * ad[ct + 4];
      }
      vs0[r] = qsum(s0); vs1[r] = qsum(s1);
      vd0[r] = qsum(d0); vd1[r] = qsum(d1);
    }
#pragma unroll
    for (int r = 0; r < 4; r++){
      int node = nbw + quad * 4 + r;
      if (node < n){
#pragma unroll
        for (int ct = 0; ct < 4; ct++)
          xh1p[(size_t)node * 64 + ct * 16 + c16] = packbf2(acc[ct][r], acc[ct + 4][r]);
      }
    }
    if (c16 == 0){
#pragma unroll
      for (int r = 0; r < 4; r++){
        int node = nbw + quad * 4 + r;
        if (node < n){
          ssrc1[node * 2]     = vs0[r];
          ssrc1[node * 2 + 1] = vs1[r];
          sdst1[node * 2]     = vd0[r];
          sdst1[node * 2 + 1] = vd1[r];
        }
      }
    }
  }
}

// ---------------- Layer-2 GEMM via MFMA: xh2 = h1(bf16) @ W2(hi+lo) + logits ----------------
__global__ __launch_bounds__(256) void k_gemm2m(
    const unsigned* __restrict__ h1p,
    const unsigned short* __restrict__ whi, const unsigned short* __restrict__ wlo,
    const void* __restrict__ a_src2, const void* __restrict__ a_dst2,
    const int* __restrict__ flagp,
    unsigned short* __restrict__ xh2b, float* __restrict__ ssrc2, float* __restrict__ sdst2, int n){
  const int f = *flagp;
  int t = threadIdx.x;
  int lane = t & 63, w = t >> 6;
  int c16 = lane & 15, quad = lane >> 4;
  int nbw = blockIdx.x * 64 + w * 16;
  int an = min(nbw + c16, n - 1);
  f32x4 acc[4];
#pragma unroll
  for (int ct = 0; ct < 4; ct++)
#pragma unroll
    for (int r = 0; r < 4; r++) acc[ct][r] = 0.f;

#pragma unroll
  for (int kc = 0; kc < 4; kc++){
    const uint4* hp = (const uint4*)h1p;
    uint4 v = hp[(size_t)an * 16 + kc * 4 + quad];
    short8 ahi;
    ahi[0] = (short)(v.x & 0xffff); ahi[1] = (short)(v.x >> 16);
    ahi[2] = (short)(v.y & 0xffff); ahi[3] = (short)(v.y >> 16);
    ahi[4] = (short)(v.z & 0xffff); ahi[5] = (short)(v.z >> 16);
    ahi[6] = (short)(v.w & 0xffff); ahi[7] = (short)(v.w >> 16);
#pragma unroll
    for (int ct = 0; ct < 4; ct++){
      const short8 bhi = *(const short8*)(whi + (((size_t)(kc * 4 + ct) * 64 + lane) << 3));
      const short8 blo = *(const short8*)(wlo + (((size_t)(kc * 4 + ct) * 64 + lane) << 3));
      acc[ct] = __builtin_amdgcn_mfma_f32_16x16x32_bf16(ahi, blo, acc[ct], 0, 0, 0);
      acc[ct] = __builtin_amdgcn_mfma_f32_16x16x32_bf16(ahi, bhi, acc[ct], 0, 0, 0);
    }
  }

  float as[4], ad[4];
#pragma unroll
  for (int ct = 0; ct < 4; ct++){
    as[ct] = ldf(a_src2, ct * 16 + c16, f);
    ad[ct] = ldf(a_dst2, ct * 16 + c16, f);
  }
  float vs[4], vd[4];
#pragma unroll
  for (int r = 0; r < 4; r++){
    float s = 0.f, d = 0.f;
#pragma unroll
    for (int ct = 0; ct < 4; ct++){
      s += acc[ct][r] * as[ct];
      d += acc[ct][r] * ad[ct];
    }
    vs[r] = qsum(s); vd[r] = qsum(d);
  }
#pragma unroll
  for (int r = 0; r < 4; r++){
    int node = nbw + quad * 4 + r;
    if (node < n){
#pragma unroll
      for (int ct = 0; ct < 4; ct++)
        xh2b[(size_t)node * 64 + ct * 16 + c16] = f2bf(acc[ct][r]);
    }
  }
  if (c16 == 0){
#pragma unroll
    for (int r = 0; r < 4; r++){
      int node = nbw + quad * 4 + r;
      if (node < n){ ssrc2[node] = vs[r]; sdst2[node] = vd[r]; }
    }
  }
}

// ---------------- Layer-1 aggregation v7: R2 shell, gather group width 8 -> 10 ----------------
// Single-variable change vs R2: pairs~17 -> ceil(17/10)=2 vmcnt windows (was 3) for 90% of
// nodes (deg<=40). Staging padded to 80 slots (max slot at width 10 = 2*39+1 = 79); pad pairs
// carry q=0 / slot-0 (L1-hot) exactly like R2's phantom semantics. Expected VGPR ~46 (R2=36;
// empirically bad zone starts ~50-60 -> do NOT widen further without checking occupancy).
__global__ __launch_bounds__(256) void k_agg1(
    const int* __restrict__ offs, const int* __restrict__ deg, const int* __restrict__ csr,
    const float2* __restrict__ ssrc, const float2* __restrict__ sdst,
    const unsigned* __restrict__ xh1p, const void* __restrict__ b1,
    const int* __restrict__ flagp, unsigned* __restrict__ h1p, int n){
  __shared__ float4 stg[4][80];   // wave-private (s, p0, p1, -); [64..79] = zero pad
  int wv = threadIdx.x >> 6;
  int wid = (int)(((size_t)blockIdx.x * blockDim.x + threadIdx.x) >> 6);
  int lane = threadIdx.x & 63;
  if (wid >= n) return;
  int st = offs[wid], d = deg[wid];
  int half = lane >> 5, u = lane & 31;
  if (lane < 16){ float4 z; z.x = __uint_as_float(0u); z.y = 0.f; z.z = 0.f; z.w = 0.f; stg[wv][64 + lane] = z; }
  float2 sd = sdst[wid];
  const char* __restrict__ xb = (const char*)xh1p;
  const unsigned uoff = (unsigned)u * 8u;   // uint2 per lane within the 256B row
  float Z0l = 0.f, Z1l = 0.f;
  float a0x = 0.f, a0y = 0.f, a1x = 0.f, a1y = 0.f;
  for (int base = 0; base < d; base += 64){
    int idx = base + lane;
    bool val = idx < d;
    int s = csr[st + (val ? idx : 0)];
    float2 sv = ssrc[s];
    float e0 = fminf(lrelu(sv.x + sd.x), 80.f);
    float e1 = fminf(lrelu(sv.y + sd.y), 80.f);
    float p0 = val ? __expf(e0) : 0.f;
    float p1 = val ? __expf(e1) : 0.f;
    Z0l += p0; Z1l += p1;
    // stage (s, p0, p1) once; broadcast via uniform ds_read_b128 (replaces 3 bpermutes/pair)
    float4 tv; tv.x = __uint_as_float((unsigned)s); tv.y = p0; tv.z = p1; tv.w = 0.f;
    stg[wv][lane] = tv;
    int cnt = min(64, d - base);
    int pairs = (cnt + 1) >> 1;
    for (int pj = 0; pj < pairs; pj += 10){
      unsigned offv[10]; float q0v[10], q1v[10]; uint2 vv[10];
#pragma unroll
      for (int k = 0; k < 10; k++){
        int jj = ((pj + k) << 1) + half;     // <= 2*(30+9)+1 = 79 < 80 (pad)
        float4 v = stg[wv][jj];
        offv[k] = (__float_as_uint(v.x) << 8) + uoff;
        q0v[k] = v.y;
        q1v[k] = v.z;
      }
#pragma unroll
      for (int k = 0; k < 10; k++)
        vv[k] = *(const uint2*)(xb + offv[k]);
#pragma unroll
      for (int k = 0; k < 10; k++){
        a0x = fmaf(q0v[k], unlo(vv[k].x), a0x); a0y = fmaf(q0v[k], unlo(vv[k].y), a0y);
        a1x = fmaf(q1v[k], unhi(vv[k].x), a1x); a1y = fmaf(q1v[k], unhi(vv[k].y), a1y);
      }
    }
  }
  a0x += __shfl_xor(a0x, 32); a0y += __shfl_xor(a0y, 32);
  a1x += __shfl_xor(a1x, 32); a1y += __shfl_xor(a1y, 32);
  float Z0 = wsum(Z0l), Z1 = wsum(Z1l);
  const int f = *flagp;
  float Zh = half ? Z1 : Z0;
  float ax = half ? a1x : a0x;
  float ay = half ? a1y : a0y;
  float inv = 1.f / (Zh + 1e-16f);
  float bx = ldf(b1, half * 64 + 2 * u, f);
  float by = ldf(b1, half * 64 + 2 * u + 1, f);
  float ox = fmaxf(ax * inv + bx, 0.f);
  float oy = fmaxf(ay * inv + by, 0.f);
  // packed bf16 pair store: pair index c = half*32+u <-> channels {2c, 2c+1}
  h1p[(size_t)wid * 64 + half * 32 + u] = packbf2(ox, oy);
}

// ---------------- Layer-2 aggregation + fused heads: R2-exact (control kernel) ----------------
__global__ __launch_bounds__(256) void k_agg2(
    const int* __restrict__ offs, const int* __restrict__ deg, const int* __restrict__ csr,
    const float* __restrict__ ssrc, const float* __restrict__ sdstA,
    const unsigned short* __restrict__ xh2b, const void* __restrict__ bias2,
    const void* __restrict__ Wm, const void* __restrict__ bm,
    const void* __restrict__ Wlos, const void* __restrict__ bl,
    const int* __restrict__ flagp, void* __restrict__ out, int n){
  __shared__ float2 stg[4][96];   // wave-private (s, p); [64..95] = zero pad
  int wv = threadIdx.x >> 6;
  int wid = (int)(((size_t)blockIdx.x * blockDim.x + threadIdx.x) >> 6);
  int lane = threadIdx.x & 63;
  if (wid >= n) return;
  int st = offs[wid], d = deg[wid];
  int half = lane >> 5, u = lane & 31;
  if (lane < 32){ float2 z; z.x = __uint_as_float(0u); z.y = 0.f; stg[wv][64 + lane] = z; }
  float sd = sdstA[wid];
  const char* __restrict__ xb = (const char*)xh2b;
  const unsigned uoff = (unsigned)u * 4u;   // packed bf16 pair per lane within the 128B row
  float Zl = 0.f, ax = 0.f, ay = 0.f;
  for (int base = 0; base < d; base += 64){
    int idx = base + lane;
    bool val = idx < d;
    int s = csr[st + (val ? idx : 0)];
    float e = fminf(lrelu(ssrc[s] + sd), 80.f);
    float pw = val ? __expf(e) : 0.f;
    Zl += pw;
    float2 tv; tv.x = __uint_as_float((unsigned)s); tv.y = pw;
    stg[wv][lane] = tv;
    int cnt = min(64, d - base);
    int pairs = (cnt + 1) >> 1;
    for (int pj = 0; pj < pairs; pj += 12){
      unsigned offv[12]; float qv[12]; unsigned vv[12];
#pragma unroll
      for (int k = 0; k < 12; k++){
        int jj = ((pj + k) << 1) + half;     // <= 2*(31+11)+1 = 85 < 96 (pad)
        float2 v = stg[wv][jj];
        offv[k] = (__float_as_uint(v.x) << 7) + uoff;
        qv[k] = v.y;
      }
#pragma unroll
      for (int k = 0; k < 12; k++)
        vv[k] = *(const unsigned*)(xb + offv[k]);
#pragma unroll
      for (int k = 0; k < 12; k++){
        ax = fmaf(qv[k], unlo(vv[k]), ax);
        ay = fmaf(qv[k], unhi(vv[k]), ay);
      }
    }
  }
  ax += __shfl_xor(ax, 32);
  ay += __shfl_xor(ay, 32);
  float Z = wsum(Zl);
  const int f = *flagp;
  float inv = 1.f / (Z + 1e-16f);
  float hx = fmaxf(ax * inv + ldf(bias2, 2 * u, f), 0.f);
  float hy = fmaxf(ay * inv + ldf(bias2, 2 * u + 1, f), 0.f);
  bool lo32 = (half == 0);
  float mo = wsum(lo32 ? hx * ldf(Wm, 2 * u, f) + hy * ldf(Wm, 2 * u + 1, f) : 0.f);
  float l0 = wsum(lo32 ? hx * ldf(Wlos, (2 * u) * 4 + 0, f) + hy * ldf(Wlos, (2 * u + 1) * 4 + 0, f) : 0.f);
  float l1 = wsum(lo32 ? hx * ldf(Wlos, (2 * u) * 4 + 1, f) + hy * ldf(Wlos, (2 * u + 1) * 4 + 1, f) : 0.f);
  float l2 = wsum(lo32 ? hx * ldf(Wlos, (2 * u) * 4 + 2, f) + hy * ldf(Wlos, (2 * u + 1) * 4 + 2, f) : 0.f);
  float l3 = wsum(lo32 ? hx * ldf(Wlos, (2 * u) * 4 + 3, f) + hy * ldf(Wlos, (2 * u + 1) * 4 + 3, f) : 0.f);
  if (lane == 0){
    float vm = mo + ldf(bm, 0, f);
    float v0 = l0 + ldf(bl, 0, f);
    float v1 = l1 + ldf(bl, 1, f);
    float v2 = l2 + ldf(bl, 2, f);
    float v3 = l3 + ldf(bl, 3, f);
    if (f){
      float* o = (float*)out;
      o[wid] = vm;
      float4 lv = make_float4(v0, v1, v2, v3);
      *(float4*)&o[n + wid * 4] = lv;
    } else {
      bf16* o = (bf16*)out;
      o[wid] = __float2bfloat16(vm);
      o[n + wid * 4 + 0] = __float2bfloat16(v0); o[n + wid * 4 + 1] = __float2bfloat16(v1);
      o[n + wid * 4 + 2] = __float2bfloat16(v2); o[n + wid * 4 + 3] = __float2bfloat16(v3);
    }
  }
}

extern "C" void kernel_launch(void* const* d_in, const int* in_sizes, int n_in,
                              void* d_out, int out_size, void* d_ws, size_t ws_size,
                              hipStream_t stream){
  const void* x      = d_in[0];
  const int*  ei     = (const int*)d_in[1];
  const void* W1     = d_in[2];
  const void* a_src1 = d_in[3];
  const void* a_dst1 = d_in[4];
  const void* b1     = d_in[5];
  const void* W2     = d_in[6];
  const void* a_src2 = d_in[7];
  const void* a_dst2 = d_in[8];
  const void* bias2  = d_in[9];
  const void* Wm     = d_in[10];
  const void* bm     = d_in[11];
  const void* Wlos   = d_in[12];
  const void* bl     = d_in[13];

  const int N = in_sizes[0] / 128;
  const int E = in_sizes[1] / 2;
  const int Etot = E + N;
  const int NBUCK = (N + 255) >> 8;

  char* base = (char*)d_ws;
  size_t off = 0;
  auto alloc = [&](size_t bytes) -> void* {
    void* r = base + off;
    off += (bytes + 255) & ~(size_t)255;
    return r;
  };
  int*      flag  = (int*)alloc(256);
  unsigned* xh1p  = (unsigned*)alloc((size_t)N * 64 * 4);   // packed bf16x2 (both heads)
  unsigned* h1p   = (unsigned*)alloc((size_t)N * 64 * 4);   // h1 packed bf16 pairs
  float*    ssrc1 = (float*)alloc((size_t)N * 2 * 4);
  float*    sdst1 = (float*)alloc((size_t)N * 2 * 4);
  float*    ssrc2 = (float*)alloc((size_t)N * 4);
  float*    sdst2 = (float*)alloc((size_t)N * 4);
  int*      deg    = (int*)alloc((size_t)N * 4);
  int*      offsb  = (int*)alloc((size_t)N * 4);
  unsigned* binned = (unsigned*)alloc((size_t)NBUCK * CAP * 4);
  int*      csr    = (int*)alloc((size_t)NBUCK * CAP * 4);
  int*      bucketCur = (int*)alloc(1024);
  unsigned short* w1hi = (unsigned short*)alloc(16384 * 2);
  unsigned short* w1lo = (unsigned short*)alloc(16384 * 2);
  unsigned short* w2hi = (unsigned short*)alloc(8192 * 2);
  unsigned short* w2lo = (unsigned short*)alloc(8192 * 2);
  unsigned short* xh2b = (unsigned short*)xh1p;   // reuse after k_agg1

  const int nchunk = (Etot + CHUNK - 1) / CHUNK;
  const int ngemm1 = (N + 63) / 64;

  // zero bucket cursors (stream op, capture-safe)
  hipMemsetAsync(bucketCur, 0, (size_t)NBUCK * 4, stream);

  // Launch A: prepw2 (w/ inline dtype probe, flag publish) || binscatter
  k_prep_scatter<<<PREPB + nchunk, 256, 0, stream>>>(
      (const unsigned short*)x, W1, W2, flag, w1hi, w1lo, w2hi, w2lo,
      ei, bucketCur, binned, E, Etot);

  // Launch B: bucketsort || gemm1m
  k_sort_gemm1<<<NBUCK + ngemm1, 256, 0, stream>>>(
      bucketCur, binned, deg, offsb, csr, NBUCK,
      x, w1hi, w1lo, a_src1, a_dst1, flag, xh1p, ssrc1, sdst1, N);

  // Layer 1 aggregation (outputs packed bf16 h1)
  k_agg1<<<(N + 3) / 4, 256, 0, stream>>>(offsb, deg, csr, (const float2*)ssrc1, (const float2*)sdst1,
                                          xh1p, b1, flag, h1p, N);

  // Layer 2
  k_gemm2m<<<(N + 63) / 64, 256, 0, stream>>>(h1p, w2hi, w2lo, a_src2, a_dst2, flag, xh2b, ssrc2, sdst2, N);
  k_agg2<<<(N + 3) / 4, 256, 0, stream>>>(offsb, deg, csr, ssrc2, sdst2, xh2b, bias2,
                                          Wm, bm, Wlos, bl, flag, d_out, N);
}